// Round 10
// baseline (1263.519 us; speedup 1.0000x reference)
//
#include <hip/hip_runtime.h>

// JIIF fused pipeline v18 = v17 with gemm_l12 widened to 1024 threads
// (16 waves -> 4 waves/SIMD) at the SAME tile/schedule.
//   R9 evidence: total 1093us; gemm_l12 167.4us, MfmaUtil 35, real VALU ~5%
//   (VALUBusy 40 incl. MFMA issue). Wall 6280 cyc/tile vs 2483 MFMA floor:
//   ~60% stall. At 2 waves/SIMD (160KB -> 1 block/CU; 124+128 regs), both
//   waves are barrier-locked in lockstep -> no wave to hide ds latency /
//   waitcnt under. Occupancy wall is the binding constraint.
// v18: same BM=128xBN=512xBK=64, same v14 one-barrier schedule; wave grid
//   2Mx8N (per-wave 64x64). Per-wave state halves: acc 64 regs, frags 32,
//   gathers 4 (1 CONS row/thread), stages 4. Peak liveness ~124 <= the
//   128-reg budget __launch_bounds__(1024,4) enforces. Ledger: vmcnt(4)
//   at each gate (4 stages older + 4 gathers newer).
// NOTES:
//  - R1(v10): 2-barrier 8-phase = null -> barrier count was the blocker.
//  - R2(v11): 1-barrier quadrant 256^2 -> <39.6us (~930 TF).
//  - R3(v12): BM=128xBN=256 fusion FAIL (amortization halved + CONS x2).
//  - R4(v13): construction serialized = 657 TF.
//  - R6(v14): CONS under MFMA shadow = total 1205us.
//  - R7(v15): MFMA-before-barrier REGRESSED. RULE: barrier -> register-ready
//    MFMA; never dependent ds_reads right after a barrier.
//  - R8(v16): tail34 @ BM=128/512thr/80KB -> 1103us.
//  - R9(v17): native cvt f2bf -> 1093us. BEST.
//  - Failure mode here: spill (VGPR at 128 cap + scratch) -> revert geometry.

typedef unsigned short u16;
typedef unsigned int   u32;
typedef __bf16  bf16x8 __attribute__((ext_vector_type(8)));
typedef float   f32x4  __attribute__((ext_vector_type(4)));
typedef unsigned short u16x8 __attribute__((ext_vector_type(8)));

__device__ __forceinline__ u16 f2bf(float f) {
  __bf16 h = (__bf16)f;                    // native v_cvt_pk_bf16_f32 (RNE)
  return __builtin_bit_cast(u16, h);
}
__device__ __forceinline__ float bf2f(u16 v) {
  return __uint_as_float(((u32)v) << 16);
}
__device__ __forceinline__ void gload_lds16(const void* g, void* l) {
  __builtin_amdgcn_global_load_lds(
      (const __attribute__((address_space(1))) void*)g,
      (__attribute__((address_space(3))) void*)l, 16, 0, 0);
}

// ---------------------------------------------------------------------------
// gather_hr: per-pixel Xhr row (q_guide_hr, bf16[128]) + cellidx[pix][4] + rel[pix][4][2]
// ---------------------------------------------------------------------------
__global__ __launch_bounds__(256)
void gather_hr(const float* __restrict__ coord, const float* __restrict__ hr,
               u16* __restrict__ Xhr, int* __restrict__ cellidx, float* __restrict__ rel)
{
  __shared__ u16 hrT[64 * 130];
  __shared__ int nhrS[64];

  const int tid = threadIdx.x;
  const int pb  = blockIdx.x << 6;        // global pixel base
  const int b   = pb >> 16;
  const int n0  = pb & 65535;
  const float rh = 0.015625f;             // 1/64

  if (tid < 64) {
    const int n = n0 + tid;
    const float cy = coord[(size_t)(b * 65536 + n) * 2 + 0];
    const float cx = coord[(size_t)(b * 65536 + n) * 2 + 1];
    float fyh = (cy + 1.0f) * 128.0f - 0.5f;
    float fxh = (cx + 1.0f) * 128.0f - 0.5f;
    int iyh = (int)floorf(fyh + 0.5f);
    int ixh = (int)floorf(fxh + 0.5f);
    bool vh = (iyh >= 0 && iyh < 256 && ixh >= 0 && ixh < 256);
    nhrS[tid] = vh ? ((iyh << 8) + ixh) : -1;
#pragma unroll
    for (int k = 0; k < 4; ++k) {
      const float vx = (k < 2) ? -1.0f : 1.0f;
      const float vy = (k & 1) ? 1.0f : -1.0f;
      const float cyk = cy + vx * rh;
      const float cxk = cx + vy * rh;
      float fy = (cyk + 1.0f) * 32.0f - 0.5f;
      float fx = (cxk + 1.0f) * 32.0f - 0.5f;
      int iy = (int)floorf(fy + 0.5f);
      int ix = (int)floorf(fx + 0.5f);
      bool valid = (iy >= 0 && iy < 64 && ix >= 0 && ix < 64);
      int iyc = min(max(iy, 0), 63);
      int ixc = min(max(ix, 0), 63);
      float qy = valid ? ((-1.0f + rh) + (2.0f * rh) * (float)iyc) : 0.0f;
      float qx = valid ? ((-1.0f + rh) + (2.0f * rh) * (float)ixc) : 0.0f;
      const int p4 = ((pb + tid) << 2) + k;
      rel[2 * p4 + 0] = (cy - qy) * 64.0f;
      rel[2 * p4 + 1] = (cx - qx) * 64.0f;
      cellidx[p4] = valid ? (b * 4096 + iyc * 64 + ixc) : -1;
    }
  }
  __syncthreads();

  const size_t hb = (size_t)b * 128 * 65536;
  for (int e = tid; e < 64 * 128; e += 256) {
    const int pix = e & 63, c = e >> 6;
    const int n = nhrS[pix];
    const float v = (n >= 0) ? hr[hb + (size_t)c * 65536 + n] : 0.0f;
    hrT[pix * 130 + c] = f2bf(v);
  }
  __syncthreads();

  for (int e = tid; e < 64 * 128; e += 256) {
    const int pix = e >> 7, c = e & 127;
    Xhr[(size_t)(pb + pix) * 128 + c] = hrT[pix * 130 + c];
  }
}

// ---------------------------------------------------------------------------
// prep_cells: Xcell[cell][0:128]=feat, [128:256]=-lr  (bf16)
// ---------------------------------------------------------------------------
__global__ __launch_bounds__(256)
void prep_cells(const float* __restrict__ feat, const float* __restrict__ lr,
                u16* __restrict__ Xcell)
{
  __shared__ u16 t[64 * 258];
  const int tid = threadIdx.x;
  const int cb = blockIdx.x << 6;
  const int b = cb >> 12;
  const int local = cb & 4095;
  const size_t fb = (size_t)b * 128 * 4096;
  for (int e = tid; e < 64 * 128; e += 256) {
    const int cell = e & 63, c = e >> 6;
    const size_t idx = fb + (size_t)c * 4096 + local + cell;
    t[cell * 258 + c]       = f2bf(feat[idx]);
    t[cell * 258 + 128 + c] = (u16)(f2bf(lr[idx]) ^ 0x8000u);
  }
  __syncthreads();
  for (int e = tid; e < 64 * 256; e += 256) {
    const int cell = e >> 8, c = e & 255;
    Xcell[(size_t)(cb + cell) * 256 + c] = t[cell * 258 + c];
  }
}

// ---------------------------------------------------------------------------
// bf16 MFMA GEMM; BK=64 via two 32-k LDS slabs; 128x128 tile.
// MODE 0: C = relu(A@B^T + bias);  MODE 1: C = A@B^T + bias (no relu);
// MODE 3: C = A@B^T (raw). All bf16 out.
// ---------------------------------------------------------------------------
template<int MODE>
__global__ __launch_bounds__(256)
void gemm_bt(const u16* __restrict__ A, const u16* __restrict__ BT,
             void* __restrict__ Cout, const float* __restrict__ bias,
             int M, int N, int K)
{
  __shared__ __align__(16) u16 sh[16384];
  u16* As = sh;
  u16* Bs = sh + 8192;

  const int tid = threadIdx.x;
  const int w = tid >> 6;
  const int lane = tid & 63;
  const int ntn = N >> 7;
  const int nmt = M >> 7;
  int bm, bn;
  if ((nmt & 7) == 0) {
    const int xcd = blockIdx.x & 7;
    const int t = blockIdx.x >> 3;
    bn = t % ntn;
    bm = xcd * (nmt >> 3) + t / ntn;
  } else {
    bm = blockIdx.x / ntn;
    bn = blockIdx.x - bm * ntn;
  }
  const int m0 = bm << 7, n0 = bn << 7;

  const int lrow = tid >> 2;
  const int cc   = tid & 3;
  const int gcol = (cc ^ ((lrow >> 1) & 3)) << 3;

  f32x4 acc[4][4];
#pragma unroll
  for (int ii = 0; ii < 4; ++ii)
#pragma unroll
    for (int jj = 0; jj < 4; ++jj)
      acc[ii][jj] = f32x4{0.f, 0.f, 0.f, 0.f};

  const int mbase = (w & 1) << 6;
  const int nbase = (w >> 1) << 6;
  const int fr = lane & 15;
  const int fq = lane >> 4;
  const int rchunk = (fq ^ ((fr >> 1) & 3)) << 3;

  for (int kt = 0; kt < K; kt += 64) {
#pragma unroll
    for (int s = 0; s < 2; ++s) {
      const int kb = kt + (s << 5);
#pragma unroll
      for (int q = 0; q < 2; ++q) {
        const int mrow = (q << 6) + lrow;
        gload_lds16(A + (size_t)(m0 + mrow) * K + (kb + gcol),
                    (char*)As + (s << 13) + (q << 12) + (w << 10));
        gload_lds16(BT + (size_t)(n0 + mrow) * K + (kb + gcol),
                    (char*)Bs + (s << 13) + (q << 12) + (w << 10));
      }
    }
    __syncthreads();
#pragma unroll
    for (int s = 0; s < 2; ++s) {
      const int so = s << 12;
      bf16x8 af[4], bfv[4];
#pragma unroll
      for (int ii = 0; ii < 4; ++ii) {
        af[ii]  = *(const bf16x8*)(As + so + ((mbase + (ii << 4) + fr) << 5) + rchunk);
        bfv[ii] = *(const bf16x8*)(Bs + so + ((nbase + (ii << 4) + fr) << 5) + rchunk);
      }
#pragma unroll
      for (int ii = 0; ii < 4; ++ii)
#pragma unroll
        for (int jj = 0; jj < 4; ++jj)
          acc[ii][jj] = __builtin_amdgcn_mfma_f32_16x16x32_bf16(af[ii], bfv[jj], acc[ii][jj], 0, 0, 0);
    }
    __syncthreads();
  }

#pragma unroll
  for (int jj = 0; jj < 4; ++jj) {
    const int ncol = n0 + nbase + (jj << 4) + fr;
    const float bi = (MODE == 0 || MODE == 1) ? bias[ncol] : 0.f;
#pragma unroll
    for (int ii = 0; ii < 4; ++ii) {
#pragma unroll
      for (int r = 0; r < 4; ++r) {
        const int mrow = m0 + mbase + (ii << 4) + (fq << 2) + r;
        if (MODE == 0) {
          ((u16*)Cout)[(size_t)mrow * N + ncol] = f2bf(fmaxf(acc[ii][jj][r] + bi, 0.f));
        } else if (MODE == 1) {
          ((u16*)Cout)[(size_t)mrow * N + ncol] = f2bf(acc[ii][jj][r] + bi);
        } else {
          ((u16*)Cout)[(size_t)mrow * N + ncol] = f2bf(acc[ii][jj][r]);
        }
      }
    }
  }
}

// ---------------------------------------------------------------------------
// gemm_l12: fused expand(layer-1 combine) + layer-2 GEMM.  N=512 fixed.
//   C = relu(A1 @ W2T^T + b2), A1 row rr (pixel p=rr>>2, branch k=rr&3):
//     A1[rr][c] = relu(Yhrb[p][c] + mask*Ycell[cell[p][k]][c]
//                      + ry*w1rel0[c] + rx*w1rel1[c])      (Yhrb = Yhr + b1)
//   BM=128, BN=512, BK=64, 1024 threads / 16 waves (2M x 8N, 64x64/wave).
//   LDS 160KB: A 2x[128][64] u16 @0; B 2x[512][64] u16 @byte 32768.
//   v14 schedule, per-wave counts halved:
//   P0: frag ks0 (8 ds_read); STAGE_B(t+1) [4 DMA]; setprio{16 MFMA ks0};
//       A_CONS(t+1) [1 row/thread; gather-wait after MFMA issue].
//   P1: frag ks1; A_LOADS(t+2) [4 gathers]; vmcnt(4) [forces the 4 stages];
//       lgkm(0); s_barrier; setprio{16 MFMA ks1}  <- register-ready MFMA.
// ---------------------------------------------------------------------------
__global__ __launch_bounds__(1024, 4)
void gemm_l12(const u16* __restrict__ Yhr, const u16* __restrict__ Ycell,
              const u16* __restrict__ W1rb, const int* __restrict__ cellidx,
              const float* __restrict__ rel, const u16* __restrict__ BT,
              u16* __restrict__ Cout, const float* __restrict__ bias,
              int M, int K, int gp0)
{
  __shared__ __align__(16) u16 sh[81920];   // 160 KB
  char* shb = (char*)sh;
  const int N = 512;

  const int tid  = threadIdx.x;
  const int w    = tid >> 6;                // 0..15
  const int lane = tid & 63;
  const int wm = w >> 3, wn = w & 7;        // 2M x 8N
  const int nwg = M >> 7;
  int bid = blockIdx.x;
  if ((nwg & 7) == 0) {
    const int cpx = nwg >> 3;
    bid = (bid & 7) * cpx + (bid >> 3);     // bijective XCD swizzle
  }
  const int m0 = bid << 7;
  const int NT = K >> 6;

  // staging/construction thread mapping (1 row/thread)
  const int srow = tid >> 3;                // 0..127
  const int cg   = tid & 7;
  const int gk   = (cg ^ (srow & 7)) << 3;  // swizzled source k offset (u16)
  const int swz8 = gk;                      // swizzled LDS chunk (u16)

  // fragment mapping
  const int fr = lane & 15;
  const int fq = lane >> 4;
  const int pk0 = ((fq)     ^ (fr & 7)) << 3;
  const int pk1 = ((4 + fq) ^ (fr & 7)) << 3;
  const int awr = (wm << 6) + fr;           // A frag row base (BM=128)
  const int bwr = (wn << 6) + fr;           // B frag row base (BN=512)

  // per-row persistent gather state (1 row: rr = srow)
  const int m04 = m0 >> 2;
  const int kk  = srow & 3;
  const int pA  = m04 + (srow >> 2);        // 32 pixels per 128-row block
  const int idxA = (gp0 + pA) * 4 + kk;
  const int cellA = cellidx[idxA];
  const float2 rvA = *(const float2*)(rel + (size_t)idxA * 2);
  const float ryA = rvA.x, rxA = rvA.y;
  const u16 mkA = (u16)(cellA >= 0 ? 0xFFFFu : 0u);
  const u16x8 mskA = {mkA, mkA, mkA, mkA, mkA, mkA, mkA, mkA};
  const u16* yA = Yhr + (size_t)pA * 1024;
  const u16* zA = Ycell + (size_t)max(cellA, 0) * 1024;

  u16x8 yhA, ycA, cw0, cw1;

#define A_LOADS(kt1_) do { const int co_ = (kt1_) + (cg << 3); \
    yhA = *(const u16x8*)(yA + co_); ycA = *(const u16x8*)(zA + co_); \
    cw0 = *(const u16x8*)(W1rb + co_); cw1 = *(const u16x8*)(W1rb + 1024 + co_); } while (0)

#define A_CONS(ab_) do { \
    const u16x8 za_ = ycA & mskA; \
    u16x8 oA_; \
    _Pragma("unroll") \
    for (int j_ = 0; j_ < 8; ++j_) { \
      float vA_ = bf2f(yhA[j_]) + bf2f(za_[j_]) + ryA * bf2f(cw0[j_]) + rxA * bf2f(cw1[j_]); \
      oA_[j_] = f2bf(fmaxf(vA_, 0.f)); \
    } \
    *(u16x8*)(sh + (ab_) + (srow << 6) + swz8) = oA_; } while (0)

// 4 sub-stages cover B rows h*128+srow; dest byte 32768 + q*65536 + h*16384 + w*1024
#define STAGE_B(q_, kt_) do { \
    _Pragma("unroll") \
    for (int h_ = 0; h_ < 4; ++h_) \
      gload_lds16(BT + (size_t)((h_ << 7) + srow) * K + (kt_) + gk, \
                  shb + 32768 + ((q_) << 16) + (h_ << 14) + (w << 10)); } while (0)
#define BAR12()   asm volatile("s_barrier" ::: "memory")
#define VMC(n)    asm volatile("s_waitcnt vmcnt(" #n ")" ::: "memory")
#define LGKM0_()  asm volatile("s_waitcnt lgkmcnt(0)" ::: "memory")

  f32x4 acc[4][4];
#pragma unroll
  for (int i = 0; i < 4; ++i)
#pragma unroll
    for (int j = 0; j < 4; ++j)
      acc[i][j] = f32x4{0.f, 0.f, 0.f, 0.f};

  // ---- prologue: build A(0)->buf0, stage B(0)->buf0, prefetch A(1) regs ----
  A_LOADS(0);
  A_CONS(0);                 // compiler waits the 4 gathers
  STAGE_B(0, 0);             // 4 stages (older than next gathers)
  if (NT > 1) { A_LOADS(64); VMC(4); }   // force stages; A(1) stays in flight
  else VMC(0);
  LGKM0_();
  BAR12();

  for (int t = 0; t < NT; ++t) {
    const int Ab = (t & 1) << 13;           // u16 offset of A buf (16KB each)
    const int Bb = 16384 + ((t & 1) << 15); // u16 offset of B buf (64KB each)
    const int p1 = (t + 1) & 1;
    const int kt1 = (t + 1) << 6;
    const bool mA_ = (t + 1 < NT);
    const bool mG_ = (t + 2 < NT);

    // ---- P0: k-slice 0 ----
    bf16x8 a0[4], g0[4];
#pragma unroll
    for (int i = 0; i < 4; ++i)
      a0[i] = *(const bf16x8*)(sh + Ab + ((awr + (i << 4)) << 6) + pk0);
#pragma unroll
    for (int j = 0; j < 4; ++j)
      g0[j] = *(const bf16x8*)(sh + Bb + ((bwr + (j << 4)) << 6) + pk0);
    if (mA_) STAGE_B(p1, kt1);               // 4 DMA stages, issue early
    __builtin_amdgcn_s_setprio(1);
#pragma unroll
    for (int i = 0; i < 4; ++i)
#pragma unroll
      for (int j = 0; j < 4; ++j)
        acc[i][j] = __builtin_amdgcn_mfma_f32_16x16x32_bf16(a0[i], g0[j], acc[i][j], 0, 0, 0);
    __builtin_amdgcn_s_setprio(0);
    // construction issues under the MFMA pipe shadow (gather-wait after
    // MFMA issue; writes go to Abuf(p1), last read drained at t-1 barrier)
    if (mA_) A_CONS(p1 << 13);

    // ---- P1: k-slice 1 ----
    bf16x8 a1[4], g1[4];
#pragma unroll
    for (int i = 0; i < 4; ++i)
      a1[i] = *(const bf16x8*)(sh + Ab + ((awr + (i << 4)) << 6) + pk1);
#pragma unroll
    for (int j = 0; j < 4; ++j)
      g1[j] = *(const bf16x8*)(sh + Bb + ((bwr + (j << 4)) << 6) + pk1);
    if (mG_) A_LOADS((t + 2) << 6);          // refill gather set (WAR-safe)
    if (mG_) VMC(4); else VMC(0);            // force stages; gathers in flight
    LGKM0_();                                // a1/g1 reads + CONS writes done
    BAR12();
    __builtin_amdgcn_s_setprio(1);
#pragma unroll
    for (int i = 0; i < 4; ++i)
#pragma unroll
      for (int j = 0; j < 4; ++j)
        acc[i][j] = __builtin_amdgcn_mfma_f32_16x16x32_bf16(a1[i], g1[j], acc[i][j], 0, 0, 0);
    __builtin_amdgcn_s_setprio(0);
  }

#undef A_LOADS
#undef A_CONS
#undef STAGE_B
#undef BAR12
#undef VMC
#undef LGKM0_

  // ---- epilogue: relu(acc + bias) -> bf16 ----
#pragma unroll
  for (int j = 0; j < 4; ++j) {
    const int ncol = (wn << 6) + (j << 4) + fr;
    const float bi = bias[ncol];
#pragma unroll
    for (int i = 0; i < 4; ++i) {
#pragma unroll
      for (int r = 0; r < 4; ++r) {
        const int mrow = m0 + (wm << 6) + (i << 4) + (fq << 2) + r;
        Cout[(size_t)mrow * N + ncol] = f2bf(fmaxf(acc[i][j][r] + bi, 0.f));
      }
    }
  }
}

// ---------------------------------------------------------------------------
// tail34 v2: layers 3+4+5 for a 128-row block (32 pixels), 512 thr / 8 waves.
//   LDS 80KB (2 blocks/CU): As 2x[128][32] [0,8192)u16; Bs 2x[256][32]
//   [8192,24576)u16; A3s 8x[128][32] [0,32768)u16 (aliases As/Bs after L3);
//   W4s 2x[128][32] [32768,40960)u16. Blend tile 128x136 aliases [0,17408).
// ---------------------------------------------------------------------------
__global__ __launch_bounds__(512, 4)
void tail34(const u16* __restrict__ A2, const u16* __restrict__ W3T,
            const u16* __restrict__ W4T, const float* __restrict__ b3,
            const float* __restrict__ b4, const float* __restrict__ w5,
            const float* __restrict__ b5, float* __restrict__ outp,
            int M, int gp0)
{
  __shared__ __align__(16) u16 sh[40960];   // 80 KB
  u16* As  = sh;            // [0,8192) u16
  u16* Bs  = sh + 8192;     // [8192,24576) u16
  u16* A3s = sh;            // 8 slabs x (128x32) [0,32768) u16
  u16* W4s = sh + 32768;    // 2 slabs x (128x32) [32768,40960) u16

  const int tid = threadIdx.x;
  const int w = tid >> 6;
  const int lane = tid & 63;
  const int wm = w >> 2, wn = w & 3;
  const int nmt = M >> 7;
  int bm;
  if ((nmt & 7) == 0) bm = (blockIdx.x & 7) * (nmt >> 3) + (blockIdx.x >> 3);
  else bm = blockIdx.x;
  const int m0 = bm << 7;

  const int lrow = tid >> 2;                 // 0..127
  const int cc   = tid & 3;
  const int gcol = (cc ^ ((lrow >> 1) & 3)) << 3;

  const int fr = lane & 15;
  const int fq = lane >> 4;
  const int rchunk = (fq ^ ((fr >> 1) & 3)) << 3;
  const int nb3 = wn << 6;                   // layer-3 wave col base (0..192)

  // ---------------- layer-3 (M 128, N 256, K 512) ----------------
  f32x4 acc3[4][4];
#pragma unroll
  for (int ii = 0; ii < 4; ++ii)
#pragma unroll
    for (int jj = 0; jj < 4; ++jj)
      acc3[ii][jj] = f32x4{0.f, 0.f, 0.f, 0.f};

  for (int kt = 0; kt < 512; kt += 64) {
#pragma unroll
    for (int s = 0; s < 2; ++s) {
      const int kb = kt + (s << 5);
      gload_lds16(A2 + (size_t)(m0 + lrow) * 512 + (kb + gcol),
                  (char*)As + (s << 13) + (w << 10));
#pragma unroll
      for (int q = 0; q < 2; ++q) {
        gload_lds16(W3T + (size_t)((q << 7) + lrow) * 512 + (kb + gcol),
                    (char*)Bs + (s << 14) + (q << 13) + (w << 10));
      }
    }
    __syncthreads();
#pragma unroll
    for (int s = 0; s < 2; ++s) {
      bf16x8 af[4], bfv[4];
#pragma unroll
      for (int ii = 0; ii < 4; ++ii) {
        af[ii]  = *(const bf16x8*)(As + (s << 12) + (((wm << 6) + (ii << 4) + fr) << 5) + rchunk);
        bfv[ii] = *(const bf16x8*)(Bs + (s << 13) + ((nb3 + (ii << 4) + fr) << 5) + rchunk);
      }
#pragma unroll
      for (int ii = 0; ii < 4; ++ii)
#pragma unroll
        for (int jj = 0; jj < 4; ++jj)
          acc3[ii][jj] = __builtin_amdgcn_mfma_f32_16x16x32_bf16(af[ii], bfv[jj], acc3[ii][jj], 0, 0, 0);
    }
    __syncthreads();
  }

  // ---------------- funnel: A3 = relu(acc3+b3) -> swizzled LDS slabs -------
  float b3v[4];
#pragma unroll
  for (int jj = 0; jj < 4; ++jj) b3v[jj] = b3[nb3 + (jj << 4) + fr];
#pragma unroll
  for (int jj = 0; jj < 4; ++jj) {
    const int col = nb3 + (jj << 4) + fr;    // 0..255
    const int sl = col >> 5, c = col & 31;
#pragma unroll
    for (int ii = 0; ii < 4; ++ii) {
#pragma unroll
      for (int r = 0; r < 4; ++r) {
        const int row = (wm << 6) + (ii << 4) + (fq << 2) + r;   // 0..127
        A3s[(sl << 12) + (row << 5) + (((c >> 3) ^ ((row >> 1) & 3)) << 3) + (c & 7)] =
            f2bf(fmaxf(acc3[ii][jj][r] + b3v[jj], 0.f));
      }
    }
  }

  // ---------------- layer-4 (K=256 from A3 slabs; N=128) ----------------
  f32x4 acc4[4][2];
#pragma unroll
  for (int ii = 0; ii < 4; ++ii)
#pragma unroll
    for (int jj = 0; jj < 2; ++jj)
      acc4[ii][jj] = f32x4{0.f, 0.f, 0.f, 0.f};
  const int nb4 = wn << 5;                   // 0..96

  for (int kt4 = 0; kt4 < 4; ++kt4) {
#pragma unroll
    for (int s = 0; s < 2; ++s) {
      const int kb = (kt4 << 6) + (s << 5);
      gload_lds16(W4T + (size_t)lrow * 256 + (kb + gcol),
                  (char*)W4s + (s << 13) + (w << 10));
    }
    __syncthreads();   // W4 visible; first iter also publishes the A3 funnel
#pragma unroll
    for (int s = 0; s < 2; ++s) {
      const int sl = (kt4 << 1) + s;
      bf16x8 af[4], bfv[2];
#pragma unroll
      for (int ii = 0; ii < 4; ++ii)
        af[ii] = *(const bf16x8*)(A3s + (sl << 12) + (((wm << 6) + (ii << 4) + fr) << 5) + rchunk);
#pragma unroll
      for (int jj = 0; jj < 2; ++jj)
        bfv[jj] = *(const bf16x8*)(W4s + (s << 12) + ((nb4 + (jj << 4) + fr) << 5) + rchunk);
#pragma unroll
      for (int ii = 0; ii < 4; ++ii)
#pragma unroll
        for (int jj = 0; jj < 2; ++jj)
          acc4[ii][jj] = __builtin_amdgcn_mfma_f32_16x16x32_bf16(af[ii], bfv[jj], acc4[ii][jj], 0, 0, 0);
    }
    __syncthreads();
  }

  // ---------------- layer-5 + softmax blend ----------------
  float b4v[2];
#pragma unroll
  for (int jj = 0; jj < 2; ++jj) b4v[jj] = b4[nb4 + (jj << 4) + fr];
#pragma unroll
  for (int ii = 0; ii < 4; ++ii) {
#pragma unroll
    for (int jj = 0; jj < 2; ++jj) {
      const int col = nb4 + (jj << 4) + fr;                      // 0..127
#pragma unroll
      for (int r = 0; r < 4; ++r) {
        const int row = (wm << 6) + (ii << 4) + (fq << 2) + r;   // 0..127
        sh[row * 136 + col] = f2bf(fmaxf(acc4[ii][jj][r] + b4v[jj], 0.f));
      }
    }
  }
  const int cbase = fr << 3;
  float w50[8], w51[8];
#pragma unroll
  for (int j = 0; j < 8; ++j) {
    w50[j] = w5[((cbase + j) << 1) + 0];
    w51[j] = w5[((cbase + j) << 1) + 1];
  }
  const float b50 = b5[0], b51 = b5[1];
  __syncthreads();

#pragma unroll
  for (int rep = 0; rep < 4; ++rep) {
    const int pl = (rep << 3) + w;            // block-local pixel 0..31
    const int row = (pl << 2) + fq;           // branch k = fq
    const u16x8 v = *(const u16x8*)(sh + row * 136 + cbase);
    float s0 = 0.f, s1 = 0.f;
#pragma unroll
    for (int j = 0; j < 8; ++j) {
      const float a = bf2f(v[j]);
      s0 += a * w50[j];
      s1 += a * w51[j];
    }
#pragma unroll
    for (int off = 8; off >= 1; off >>= 1) {
      s0 += __shfl_xor(s0, off, 16);
      s1 += __shfl_xor(s1, off, 16);
    }
    float p0[4], p1[4];
#pragma unroll
    for (int k = 0; k < 4; ++k) {
      p0[k] = __shfl(s0, k << 4, 64) + b50;
      p1[k] = __shfl(s1, k << 4, 64) + b51;
    }
    if (lane == 0) {
      float mx = fmaxf(fmaxf(p1[0], p1[1]), fmaxf(p1[2], p1[3]));
      float e0 = expf(p1[0] - mx), e1 = expf(p1[1] - mx);
      float e2 = expf(p1[2] - mx), e3 = expf(p1[3] - mx);
      outp[gp0 + (m0 >> 2) + pl] =
          (p0[0] * e0 + p0[1] * e1 + p0[2] * e2 + p0[3] * e3) / (e0 + e1 + e2 + e3);
    }
  }
}

// ---------------------------------------------------------------------------
// prep_all: all transposed bf16 weights in one dispatch (+ bf16 w1rel).
// ---------------------------------------------------------------------------
__global__ __launch_bounds__(256)
void prep_all(const float* __restrict__ w1, const float* __restrict__ w2,
              const float* __restrict__ w3, const float* __restrict__ w4,
              u16* __restrict__ W1hrT, u16* __restrict__ W1cellT,
              u16* __restrict__ W2T, u16* __restrict__ W3T, u16* __restrict__ W4T,
              u16* __restrict__ W1rb)
{
  const int idx = blockIdx.x * 256 + threadIdx.x;
  if (idx < 131072) {
    const int n = idx >> 7, k = idx & 127;
    W1hrT[idx] = f2bf(w1[(128 + k) * 1024 + n] + w1[(256 + k) * 1024 + n]);
  } else if (idx < 393216) {
    const int i = idx - 131072;
    const int n = i >> 8, k = i & 255;
    W1cellT[i] = f2bf((k < 128) ? w1[k * 1024 + n] : w1[(128 + k) * 1024 + n]);
  } else if (idx < 917504) {
    const int i = idx - 393216;
    const int n = i >> 10, k = i & 1023;
    W2T[i] = f2bf(w2[k * 512 + n]);
  } else if (idx < 1048576) {
    const int i = idx - 917504;
    const int n = i >> 9, k = i & 511;
    W3T[i] = f2bf(w3[k * 256 + n]);
  } else if (idx < 1081344) {
    const int i = idx - 1048576;
    const int n = i >> 8, k = i & 255;
    W4T[i] = f2bf(w4[k * 128 + n]);
  } else if (idx < 1083392) {
    const int i = idx - 1081344;
    W1rb[i] = f2bf(w1[384 * 1024 + i]);      // w1rel rows 384,385 -> bf16
  }
}

// ---------------------------------------------------------------------------
extern "C" void kernel_launch(void* const* d_in, const int* in_sizes, int n_in,
                              void* d_out, int out_size, void* d_ws, size_t ws_size,
                              hipStream_t stream)
{
  const float* feat  = (const float*)d_in[0];
  const float* coord = (const float*)d_in[1];
  const float* hrg   = (const float*)d_in[2];
  const float* lrg   = (const float*)d_in[3];
  const float* w1 = (const float*)d_in[4];
  const float* b1 = (const float*)d_in[5];
  const float* w2 = (const float*)d_in[6];
  const float* b2 = (const float*)d_in[7];
  const float* w3 = (const float*)d_in[8];
  const float* b3 = (const float*)d_in[9];
  const float* w4 = (const float*)d_in[10];
  const float* b4 = (const float*)d_in[11];
  const float* w5 = (const float*)d_in[12];
  const float* b5 = (const float*)d_in[13];
  float* out = (float*)d_out;

  char* base = (char*)d_ws;
  u16* W1hrT   = (u16*)base;                       // [1024][128]
  u16* W1cellT = W1hrT + 1024 * 128;               // [1024][256]
  u16* W2T     = W1cellT + 1024 * 256;             // [512][1024]
  u16* W3T     = W2T + 512 * 1024;                 // [256][512]
  u16* W4T     = W3T + 256 * 512;                  // [128][256]
  u16* W1rb    = W4T + 128 * 256;                  // [2][1024] bf16 w1rel
  u16* Xcell   = W1rb + 2048;                      // [8192][256]
  u16* Ycell   = Xcell + 8192 * 256;               // [8192][1024] bf16
  u16* Xhr     = Ycell + (size_t)8192 * 1024;      // [131072][128]
  float* relb  = (float*)(Xhr + (size_t)131072 * 128); // [131072][4][2]
  int* cellidx = (int*)(relb + (size_t)131072 * 8);    // [131072][4]
  char* chunk_base = (char*)(cellidx + (size_t)131072 * 4);
  const size_t fixed = (size_t)(chunk_base - base);

  const int NP = 131072;
  // per-pixel chunk bytes: Yhr 2048 + A2 4096 = 6144 (A1 fused away)
  int nc = 1;
  while (nc < 128 && fixed + (size_t)(NP / nc) * 6144ULL > ws_size) nc <<= 1;
  const int CP = NP / nc;
  const int R = CP * 4;

  u16* Yhr = (u16*)chunk_base;          // [CP][1024] bf16 (Yhr + b1 folded)
  u16* A2  = Yhr + (size_t)CP * 1024;   // [R][512] bf16

  prep_all<<<4232, 256, 0, stream>>>(w1, w2, w3, w4, W1hrT, W1cellT, W2T, W3T,
                                     W4T, W1rb);
  gather_hr<<<NP / 64, 256, 0, stream>>>(coord, hrg, Xhr, cellidx, relb);
  prep_cells<<<8192 / 64, 256, 0, stream>>>(feat, lrg, Xcell);
  // Ycell = Xcell @ W1cellT^T (raw bf16)
  gemm_bt<3><<<(8192 / 128) * (1024 / 128), 256, 0, stream>>>(
      Xcell, W1cellT, (void*)Ycell, nullptr, 8192, 1024, 256);

  for (int ch = 0; ch < nc; ++ch) {
    const int gp0 = ch * CP;
    // Yhrb = Xhr_chunk @ W1hrT^T + b1 (MODE 1: bias, no relu)
    gemm_bt<1><<<(CP / 128) * (1024 / 128), 256, 0, stream>>>(
        Xhr + (size_t)gp0 * 128, W1hrT, (void*)Yhr, b1, CP, 1024, 128);
    // fused expand + layer-2: A2 = relu(A1(Yhrb,Ycell,rel) @ W2T^T + b2)
    gemm_l12<<<(R >> 7), 1024, 0, stream>>>(
        Yhr, Ycell, W1rb, cellidx, relb, W2T, A2, b2, R, 1024, gp0);
    // layers 3+4+5: 128-row blocks, 512 threads
    tail34<<<R / 128, 512, 0, stream>>>(
        A2, W3T, W4T, b3, b4, w5, b5, out, R, gp0);
  }
}

// Round 11
// 1098.699 us; speedup vs baseline: 1.1500x; 1.1500x over previous
//
#include <hip/hip_runtime.h>

// JIIF fused pipeline v19 = v17 gemm_l12 (8-wave, REVERTED from v18) + LDS
// re-tiled coalesced epilogue.
//   R10 evidence: v18 (16 waves) REGRESSED 167->215us with Occupancy 2x and
//   MfmaUtil DOWN (35->26.9) -> occupancy was NOT the binding constraint;
//   thin waves halve the MFMA issue-shadow and add 33% LDS frag traffic.
//   RULE: fewer/fatter waves with 32-MFMA clusters win here.
//   R9 counters: WRITE_SIZE 138MB vs 33.5MB useful A2 = 4.1x amplification
//   (2B fragment-scatter stores dirty full 128B lines). v19: after the K
//   loop LDS is dead -> stage C-tile [128][512] bf16 in LDS (128KB), one
//   __syncthreads, then 16B/lane row-contiguous stores (1KB per wave-row).
// NOTES:
//  - R1(v10): 2-barrier 8-phase = null -> barrier count was the blocker.
//  - R2(v11): 1-barrier quadrant 256^2 -> <39.6us (~930 TF).
//  - R3(v12): BM=128xBN=256 fusion FAIL (amortization halved + CONS x2).
//  - R4(v13): construction serialized = 657 TF.
//  - R6(v14): CONS under MFMA shadow -> 1205us.
//  - R7(v15): MFMA-before-barrier REGRESSED. RULE: barrier -> register-ready
//    MFMA; never dependent ds_reads right after a barrier.
//  - R8(v16): tail34 @ BM=128/512thr/80KB -> 1103us.
//  - R9(v17): native cvt f2bf -> 1093us. BEST.
//  - R10(v18): 16-wave gemm_l12 REGRESSED (see above). Reverted.
//  - gemm_l12 register budget EXACTLY at 8-waves/CU cliff (124+128 acc):
//    do not add persistent VGPRs. BN must stay 512 (v12 trap).

typedef unsigned short u16;
typedef unsigned int   u32;
typedef __bf16  bf16x8 __attribute__((ext_vector_type(8)));
typedef float   f32x4  __attribute__((ext_vector_type(4)));
typedef unsigned short u16x8 __attribute__((ext_vector_type(8)));

__device__ __forceinline__ u16 f2bf(float f) {
  __bf16 h = (__bf16)f;                    // native v_cvt_pk_bf16_f32 (RNE)
  return __builtin_bit_cast(u16, h);
}
__device__ __forceinline__ float bf2f(u16 v) {
  return __uint_as_float(((u32)v) << 16);
}
__device__ __forceinline__ void gload_lds16(const void* g, void* l) {
  __builtin_amdgcn_global_load_lds(
      (const __attribute__((address_space(1))) void*)g,
      (__attribute__((address_space(3))) void*)l, 16, 0, 0);
}

// ---------------------------------------------------------------------------
// gather_hr: per-pixel Xhr row (q_guide_hr, bf16[128]) + cellidx[pix][4] + rel[pix][4][2]
// ---------------------------------------------------------------------------
__global__ __launch_bounds__(256)
void gather_hr(const float* __restrict__ coord, const float* __restrict__ hr,
               u16* __restrict__ Xhr, int* __restrict__ cellidx, float* __restrict__ rel)
{
  __shared__ u16 hrT[64 * 130];
  __shared__ int nhrS[64];

  const int tid = threadIdx.x;
  const int pb  = blockIdx.x << 6;        // global pixel base
  const int b   = pb >> 16;
  const int n0  = pb & 65535;
  const float rh = 0.015625f;             // 1/64

  if (tid < 64) {
    const int n = n0 + tid;
    const float cy = coord[(size_t)(b * 65536 + n) * 2 + 0];
    const float cx = coord[(size_t)(b * 65536 + n) * 2 + 1];
    float fyh = (cy + 1.0f) * 128.0f - 0.5f;
    float fxh = (cx + 1.0f) * 128.0f - 0.5f;
    int iyh = (int)floorf(fyh + 0.5f);
    int ixh = (int)floorf(fxh + 0.5f);
    bool vh = (iyh >= 0 && iyh < 256 && ixh >= 0 && ixh < 256);
    nhrS[tid] = vh ? ((iyh << 8) + ixh) : -1;
#pragma unroll
    for (int k = 0; k < 4; ++k) {
      const float vx = (k < 2) ? -1.0f : 1.0f;
      const float vy = (k & 1) ? 1.0f : -1.0f;
      const float cyk = cy + vx * rh;
      const float cxk = cx + vy * rh;
      float fy = (cyk + 1.0f) * 32.0f - 0.5f;
      float fx = (cxk + 1.0f) * 32.0f - 0.5f;
      int iy = (int)floorf(fy + 0.5f);
      int ix = (int)floorf(fx + 0.5f);
      bool valid = (iy >= 0 && iy < 64 && ix >= 0 && ix < 64);
      int iyc = min(max(iy, 0), 63);
      int ixc = min(max(ix, 0), 63);
      float qy = valid ? ((-1.0f + rh) + (2.0f * rh) * (float)iyc) : 0.0f;
      float qx = valid ? ((-1.0f + rh) + (2.0f * rh) * (float)ixc) : 0.0f;
      const int p4 = ((pb + tid) << 2) + k;
      rel[2 * p4 + 0] = (cy - qy) * 64.0f;
      rel[2 * p4 + 1] = (cx - qx) * 64.0f;
      cellidx[p4] = valid ? (b * 4096 + iyc * 64 + ixc) : -1;
    }
  }
  __syncthreads();

  const size_t hb = (size_t)b * 128 * 65536;
  for (int e = tid; e < 64 * 128; e += 256) {
    const int pix = e & 63, c = e >> 6;
    const int n = nhrS[pix];
    const float v = (n >= 0) ? hr[hb + (size_t)c * 65536 + n] : 0.0f;
    hrT[pix * 130 + c] = f2bf(v);
  }
  __syncthreads();

  for (int e = tid; e < 64 * 128; e += 256) {
    const int pix = e >> 7, c = e & 127;
    Xhr[(size_t)(pb + pix) * 128 + c] = hrT[pix * 130 + c];
  }
}

// ---------------------------------------------------------------------------
// prep_cells: Xcell[cell][0:128]=feat, [128:256]=-lr  (bf16)
// ---------------------------------------------------------------------------
__global__ __launch_bounds__(256)
void prep_cells(const float* __restrict__ feat, const float* __restrict__ lr,
                u16* __restrict__ Xcell)
{
  __shared__ u16 t[64 * 258];
  const int tid = threadIdx.x;
  const int cb = blockIdx.x << 6;
  const int b = cb >> 12;
  const int local = cb & 4095;
  const size_t fb = (size_t)b * 128 * 4096;
  for (int e = tid; e < 64 * 128; e += 256) {
    const int cell = e & 63, c = e >> 6;
    const size_t idx = fb + (size_t)c * 4096 + local + cell;
    t[cell * 258 + c]       = f2bf(feat[idx]);
    t[cell * 258 + 128 + c] = (u16)(f2bf(lr[idx]) ^ 0x8000u);
  }
  __syncthreads();
  for (int e = tid; e < 64 * 256; e += 256) {
    const int cell = e >> 8, c = e & 255;
    Xcell[(size_t)(cb + cell) * 256 + c] = t[cell * 258 + c];
  }
}

// ---------------------------------------------------------------------------
// bf16 MFMA GEMM; BK=64 via two 32-k LDS slabs; 128x128 tile.
// MODE 0: C = relu(A@B^T + bias);  MODE 1: C = A@B^T + bias (no relu);
// MODE 3: C = A@B^T (raw). All bf16 out.
// ---------------------------------------------------------------------------
template<int MODE>
__global__ __launch_bounds__(256)
void gemm_bt(const u16* __restrict__ A, const u16* __restrict__ BT,
             void* __restrict__ Cout, const float* __restrict__ bias,
             int M, int N, int K)
{
  __shared__ __align__(16) u16 sh[16384];
  u16* As = sh;
  u16* Bs = sh + 8192;

  const int tid = threadIdx.x;
  const int w = tid >> 6;
  const int lane = tid & 63;
  const int ntn = N >> 7;
  const int nmt = M >> 7;
  int bm, bn;
  if ((nmt & 7) == 0) {
    const int xcd = blockIdx.x & 7;
    const int t = blockIdx.x >> 3;
    bn = t % ntn;
    bm = xcd * (nmt >> 3) + t / ntn;
  } else {
    bm = blockIdx.x / ntn;
    bn = blockIdx.x - bm * ntn;
  }
  const int m0 = bm << 7, n0 = bn << 7;

  const int lrow = tid >> 2;
  const int cc   = tid & 3;
  const int gcol = (cc ^ ((lrow >> 1) & 3)) << 3;

  f32x4 acc[4][4];
#pragma unroll
  for (int ii = 0; ii < 4; ++ii)
#pragma unroll
    for (int jj = 0; jj < 4; ++jj)
      acc[ii][jj] = f32x4{0.f, 0.f, 0.f, 0.f};

  const int mbase = (w & 1) << 6;
  const int nbase = (w >> 1) << 6;
  const int fr = lane & 15;
  const int fq = lane >> 4;
  const int rchunk = (fq ^ ((fr >> 1) & 3)) << 3;

  for (int kt = 0; kt < K; kt += 64) {
#pragma unroll
    for (int s = 0; s < 2; ++s) {
      const int kb = kt + (s << 5);
#pragma unroll
      for (int q = 0; q < 2; ++q) {
        const int mrow = (q << 6) + lrow;
        gload_lds16(A + (size_t)(m0 + mrow) * K + (kb + gcol),
                    (char*)As + (s << 13) + (q << 12) + (w << 10));
        gload_lds16(BT + (size_t)(n0 + mrow) * K + (kb + gcol),
                    (char*)Bs + (s << 13) + (q << 12) + (w << 10));
      }
    }
    __syncthreads();
#pragma unroll
    for (int s = 0; s < 2; ++s) {
      const int so = s << 12;
      bf16x8 af[4], bfv[4];
#pragma unroll
      for (int ii = 0; ii < 4; ++ii) {
        af[ii]  = *(const bf16x8*)(As + so + ((mbase + (ii << 4) + fr) << 5) + rchunk);
        bfv[ii] = *(const bf16x8*)(Bs + so + ((nbase + (ii << 4) + fr) << 5) + rchunk);
      }
#pragma unroll
      for (int ii = 0; ii < 4; ++ii)
#pragma unroll
        for (int jj = 0; jj < 4; ++jj)
          acc[ii][jj] = __builtin_amdgcn_mfma_f32_16x16x32_bf16(af[ii], bfv[jj], acc[ii][jj], 0, 0, 0);
    }
    __syncthreads();
  }

#pragma unroll
  for (int jj = 0; jj < 4; ++jj) {
    const int ncol = n0 + nbase + (jj << 4) + fr;
    const float bi = (MODE == 0 || MODE == 1) ? bias[ncol] : 0.f;
#pragma unroll
    for (int ii = 0; ii < 4; ++ii) {
#pragma unroll
      for (int r = 0; r < 4; ++r) {
        const int mrow = m0 + mbase + (ii << 4) + (fq << 2) + r;
        if (MODE == 0) {
          ((u16*)Cout)[(size_t)mrow * N + ncol] = f2bf(fmaxf(acc[ii][jj][r] + bi, 0.f));
        } else if (MODE == 1) {
          ((u16*)Cout)[(size_t)mrow * N + ncol] = f2bf(acc[ii][jj][r] + bi);
        } else {
          ((u16*)Cout)[(size_t)mrow * N + ncol] = f2bf(acc[ii][jj][r]);
        }
      }
    }
  }
}

// ---------------------------------------------------------------------------
// gemm_l12: fused expand(layer-1 combine) + layer-2 GEMM.  N=512 fixed.
//   C = relu(A1 @ W2T^T + b2), A1 row rr (pixel p=rr>>2, branch k=rr&3):
//     A1[rr][c] = relu(Yhrb[p][c] + mask*Ycell[cell[p][k]][c]
//                      + ry*w1rel0[c] + rx*w1rel1[c])      (Yhrb = Yhr + b1)
//   BM=128, BN=512, BK=64, 512 threads / 8 waves; per-wave C 64x128.
//   LDS 160KB: A 2x[128][64] u16 @0; B 2x[512][64] u16 @byte 32768.
//   v14 schedule (VERBATIM from R6 winner):
//   P0: frag ks0; STAGE_B(t+1); setprio{32 MFMA ks0}; A_CONS(t+1).
//   P1: frag ks1; A_LOADS(t+2); vmcnt(6); lgkm(0); s_barrier;
//       setprio{32 MFMA ks1}   <- post-barrier MFMA is register-ready.
//   Epilogue: C-tile via LDS -> 16B/lane coalesced stores (kills 4.1x
//   write amplification; R9 WRITE_SIZE evidence).
// ---------------------------------------------------------------------------
__global__ __launch_bounds__(512, 2)
void gemm_l12(const u16* __restrict__ Yhr, const u16* __restrict__ Ycell,
              const u16* __restrict__ W1rb, const int* __restrict__ cellidx,
              const float* __restrict__ rel, const u16* __restrict__ BT,
              u16* __restrict__ Cout, const float* __restrict__ bias,
              int M, int K, int gp0)
{
  __shared__ __align__(16) u16 sh[81920];   // 160 KB
  char* shb = (char*)sh;
  const int N = 512;

  const int tid  = threadIdx.x;
  const int w    = tid >> 6;
  const int lane = tid & 63;
  const int wm = w >> 2, wn = w & 3;
  const int nwg = M >> 7;
  int bid = blockIdx.x;
  if ((nwg & 7) == 0) {
    const int cpx = nwg >> 3;
    bid = (bid & 7) * cpx + (bid >> 3);     // bijective XCD swizzle
  }
  const int m0 = bid << 7;
  const int NT = K >> 6;

  // staging/construction thread mapping
  const int srow = tid >> 3;                // 0..63
  const int cg   = tid & 7;
  const int gk   = (cg ^ (srow & 7)) << 3;  // swizzled source k offset (u16)
  const int swz8 = gk;                      // swizzled LDS chunk (u16)

  // fragment mapping
  const int fr = lane & 15;
  const int fq = lane >> 4;
  const int pk0 = ((fq)     ^ (fr & 7)) << 3;
  const int pk1 = ((4 + fq) ^ (fr & 7)) << 3;
  const int awr = (wm << 6) + fr;           // A frag row base (BM=128)
  const int bwr = (wn << 7) + fr;           // B frag row base (BN=512)

  // per-row persistent gather state (2 rows/thread: rr = srow, 64+srow)
  const int m04 = m0 >> 2;
  const int kk  = srow & 3;
  const int pA  = m04 + (srow >> 2);
  const int pB  = pA + 16;
  const int idxA = (gp0 + pA) * 4 + kk;
  const int idxB = (gp0 + pB) * 4 + kk;
  const int cellA = cellidx[idxA];
  const int cellB = cellidx[idxB];
  const float2 rvA = *(const float2*)(rel + (size_t)idxA * 2);
  const float2 rvB = *(const float2*)(rel + (size_t)idxB * 2);
  const float ryA = rvA.x, rxA = rvA.y, ryB = rvB.x, rxB = rvB.y;
  const u16 mkA = (u16)(cellA >= 0 ? 0xFFFFu : 0u);
  const u16 mkB = (u16)(cellB >= 0 ? 0xFFFFu : 0u);
  const u16x8 mskA = {mkA, mkA, mkA, mkA, mkA, mkA, mkA, mkA};
  const u16x8 mskB = {mkB, mkB, mkB, mkB, mkB, mkB, mkB, mkB};
  const u16* yA = Yhr + (size_t)pA * 1024;
  const u16* yB = Yhr + (size_t)pB * 1024;
  const u16* zA = Ycell + (size_t)max(cellA, 0) * 1024;
  const u16* zB = Ycell + (size_t)max(cellB, 0) * 1024;

  u16x8 yhA, yhB, ycA, ycB, cw0, cw1;

#define A_LOADS(kt1_) do { const int co_ = (kt1_) + (cg << 3); \
    yhA = *(const u16x8*)(yA + co_); yhB = *(const u16x8*)(yB + co_); \
    ycA = *(const u16x8*)(zA + co_); ycB = *(const u16x8*)(zB + co_); \
    cw0 = *(const u16x8*)(W1rb + co_); cw1 = *(const u16x8*)(W1rb + 1024 + co_); } while (0)

#define A_CONS(ab_) do { \
    const u16x8 za_ = ycA & mskA, zb_ = ycB & mskB; \
    u16x8 oA_, oB_; \
    _Pragma("unroll") \
    for (int j_ = 0; j_ < 8; ++j_) { \
      const float f0_ = bf2f(cw0[j_]), f1_ = bf2f(cw1[j_]); \
      float vA_ = bf2f(yhA[j_]) + bf2f(za_[j_]) + ryA * f0_ + rxA * f1_; \
      float vB_ = bf2f(yhB[j_]) + bf2f(zb_[j_]) + ryB * f0_ + rxB * f1_; \
      oA_[j_] = f2bf(fmaxf(vA_, 0.f)); \
      oB_[j_] = f2bf(fmaxf(vB_, 0.f)); \
    } \
    *(u16x8*)(sh + (ab_) + (srow << 6) + swz8) = oA_; \
    *(u16x8*)(sh + (ab_) + ((64 + srow) << 6) + swz8) = oB_; } while (0)

// 8 sub-stages cover B rows h*64+srow; dest byte 32768 + q*65536 + h*8192 + w*1024
#define STAGE_B(q_, kt_) do { \
    _Pragma("unroll") \
    for (int h_ = 0; h_ < 8; ++h_) \
      gload_lds16(BT + (size_t)((h_ << 6) + srow) * K + (kt_) + gk, \
                  shb + 32768 + ((q_) << 16) + (h_ << 13) + (w << 10)); } while (0)
#define BAR12()   asm volatile("s_barrier" ::: "memory")
#define VMC(n)    asm volatile("s_waitcnt vmcnt(" #n ")" ::: "memory")
#define LGKM0_()  asm volatile("s_waitcnt lgkmcnt(0)" ::: "memory")

  f32x4 acc[4][8];
#pragma unroll
  for (int i = 0; i < 4; ++i)
#pragma unroll
    for (int j = 0; j < 8; ++j)
      acc[i][j] = f32x4{0.f, 0.f, 0.f, 0.f};

  // ---- prologue: build A(0)->buf0, stage B(0)->buf0, prefetch A(1) regs ----
  A_LOADS(0);
  A_CONS(0);                 // compiler waits the 6 gathers
  STAGE_B(0, 0);             // 8 stages (older than next gathers)
  if (NT > 1) { A_LOADS(64); VMC(6); }   // force stages; A(1) stays in flight
  else VMC(0);
  LGKM0_();
  BAR12();

  for (int t = 0; t < NT; ++t) {
    const int Ab = (t & 1) << 13;           // u16 offset of A buf
    const int Bb = 16384 + ((t & 1) << 15); // u16 offset of B buf
    const int p1 = (t + 1) & 1;
    const int kt1 = (t + 1) << 6;
    const bool mA_ = (t + 1 < NT);
    const bool mG_ = (t + 2 < NT);

    // ---- P0: k-slice 0 ----
    bf16x8 a0[4], g0[8];
#pragma unroll
    for (int i = 0; i < 4; ++i)
      a0[i] = *(const bf16x8*)(sh + Ab + ((awr + (i << 4)) << 6) + pk0);
#pragma unroll
    for (int j = 0; j < 8; ++j)
      g0[j] = *(const bf16x8*)(sh + Bb + ((bwr + (j << 4)) << 6) + pk0);
    if (mA_) STAGE_B(p1, kt1);               // 8 DMA stages, issue early
    __builtin_amdgcn_s_setprio(1);
#pragma unroll
    for (int i = 0; i < 4; ++i)
#pragma unroll
      for (int j = 0; j < 8; ++j)
        acc[i][j] = __builtin_amdgcn_mfma_f32_16x16x32_bf16(a0[i], g0[j], acc[i][j], 0, 0, 0);
    __builtin_amdgcn_s_setprio(0);
    // construction issues under the MFMA pipe shadow (gather-wait after
    // MFMA issue; writes go to Abuf(p1), last read drained at t-1 barrier)
    if (mA_) A_CONS(p1 << 13);

    // ---- P1: k-slice 1 ----
    bf16x8 a1[4], g1[8];
#pragma unroll
    for (int i = 0; i < 4; ++i)
      a1[i] = *(const bf16x8*)(sh + Ab + ((awr + (i << 4)) << 6) + pk1);
#pragma unroll
    for (int j = 0; j < 8; ++j)
      g1[j] = *(const bf16x8*)(sh + Bb + ((bwr + (j << 4)) << 6) + pk1);
    if (mG_) A_LOADS((t + 2) << 6);          // refill gather set (WAR-safe)
    if (mG_) VMC(6); else VMC(0);            // force stages; gathers in flight
    LGKM0_();                                // a1/g1 reads + CONS writes done
    BAR12();
    __builtin_amdgcn_s_setprio(1);
#pragma unroll
    for (int i = 0; i < 4; ++i)
#pragma unroll
      for (int j = 0; j < 8; ++j)
        acc[i][j] = __builtin_amdgcn_mfma_f32_16x16x32_bf16(a1[i], g1[j], acc[i][j], 0, 0, 0);
    __builtin_amdgcn_s_setprio(0);
  }

#undef A_LOADS
#undef A_CONS
#undef STAGE_B
#undef BAR12
#undef VMC
#undef LGKM0_

  // ---- epilogue: relu(acc+bias) -> LDS C-tile -> coalesced 16B stores ----
  // (all K-loop LDS reads drained before the final barrier; each wave fills
  //  its own 64x128 sub-tile, one sync, then whole-block row copies)
#pragma unroll
  for (int j = 0; j < 8; ++j) {
    const int ncol = (wn << 7) + (j << 4) + fr;
    const float bi = bias[ncol];
#pragma unroll
    for (int i = 0; i < 4; ++i) {
#pragma unroll
      for (int r = 0; r < 4; ++r) {
        const int row = (wm << 6) + (i << 4) + (fq << 2) + r;
        sh[row * 512 + ncol] = f2bf(fmaxf(acc[i][j][r] + bi, 0.f));
      }
    }
  }
  __syncthreads();
  {
    const int c8 = (tid & 63) << 3;          // u16 col offset, 16B per lane
#pragma unroll
    for (int ps = 0; ps < 16; ++ps) {
      const int row = (ps << 3) + (tid >> 6);
      *(u16x8*)(Cout + (size_t)(m0 + row) * 512 + c8) =
          *(const u16x8*)(sh + row * 512 + c8);
    }
  }
}

// ---------------------------------------------------------------------------
// tail34 v2: layers 3+4+5 for a 128-row block (32 pixels), 512 thr / 8 waves.
//   LDS 80KB (2 blocks/CU): As 2x[128][32] [0,8192)u16; Bs 2x[256][32]
//   [8192,24576)u16; A3s 8x[128][32] [0,32768)u16 (aliases As/Bs after L3);
//   W4s 2x[128][32] [32768,40960)u16. Blend tile 128x136 aliases [0,17408).
// ---------------------------------------------------------------------------
__global__ __launch_bounds__(512, 4)
void tail34(const u16* __restrict__ A2, const u16* __restrict__ W3T,
            const u16* __restrict__ W4T, const float* __restrict__ b3,
            const float* __restrict__ b4, const float* __restrict__ w5,
            const float* __restrict__ b5, float* __restrict__ outp,
            int M, int gp0)
{
  __shared__ __align__(16) u16 sh[40960];   // 80 KB
  u16* As  = sh;            // [0,8192) u16
  u16* Bs  = sh + 8192;     // [8192,24576) u16
  u16* A3s = sh;            // 8 slabs x (128x32) [0,32768) u16
  u16* W4s = sh + 32768;    // 2 slabs x (128x32) [32768,40960) u16

  const int tid = threadIdx.x;
  const int w = tid >> 6;
  const int lane = tid & 63;
  const int wm = w >> 2, wn = w & 3;
  const int nmt = M >> 7;
  int bm;
  if ((nmt & 7) == 0) bm = (blockIdx.x & 7) * (nmt >> 3) + (blockIdx.x >> 3);
  else bm = blockIdx.x;
  const int m0 = bm << 7;

  const int lrow = tid >> 2;                 // 0..127
  const int cc   = tid & 3;
  const int gcol = (cc ^ ((lrow >> 1) & 3)) << 3;

  const int fr = lane & 15;
  const int fq = lane >> 4;
  const int rchunk = (fq ^ ((fr >> 1) & 3)) << 3;
  const int nb3 = wn << 6;                   // layer-3 wave col base (0..192)

  // ---------------- layer-3 (M 128, N 256, K 512) ----------------
  f32x4 acc3[4][4];
#pragma unroll
  for (int ii = 0; ii < 4; ++ii)
#pragma unroll
    for (int jj = 0; jj < 4; ++jj)
      acc3[ii][jj] = f32x4{0.f, 0.f, 0.f, 0.f};

  for (int kt = 0; kt < 512; kt += 64) {
#pragma unroll
    for (int s = 0; s < 2; ++s) {
      const int kb = kt + (s << 5);
      gload_lds16(A2 + (size_t)(m0 + lrow) * 512 + (kb + gcol),
                  (char*)As + (s << 13) + (w << 10));
#pragma unroll
      for (int q = 0; q < 2; ++q) {
        gload_lds16(W3T + (size_t)((q << 7) + lrow) * 512 + (kb + gcol),
                    (char*)Bs + (s << 14) + (q << 13) + (w << 10));
      }
    }
    __syncthreads();
#pragma unroll
    for (int s = 0; s < 2; ++s) {
      bf16x8 af[4], bfv[4];
#pragma unroll
      for (int ii = 0; ii < 4; ++ii) {
        af[ii]  = *(const bf16x8*)(As + (s << 12) + (((wm << 6) + (ii << 4) + fr) << 5) + rchunk);
        bfv[ii] = *(const bf16x8*)(Bs + (s << 13) + ((nb3 + (ii << 4) + fr) << 5) + rchunk);
      }
#pragma unroll
      for (int ii = 0; ii < 4; ++ii)
#pragma unroll
        for (int jj = 0; jj < 4; ++jj)
          acc3[ii][jj] = __builtin_amdgcn_mfma_f32_16x16x32_bf16(af[ii], bfv[jj], acc3[ii][jj], 0, 0, 0);
    }
    __syncthreads();
  }

  // ---------------- funnel: A3 = relu(acc3+b3) -> swizzled LDS slabs -------
  float b3v[4];
#pragma unroll
  for (int jj = 0; jj < 4; ++jj) b3v[jj] = b3[nb3 + (jj << 4) + fr];
#pragma unroll
  for (int jj = 0; jj < 4; ++jj) {
    const int col = nb3 + (jj << 4) + fr;    // 0..255
    const int sl = col >> 5, c = col & 31;
#pragma unroll
    for (int ii = 0; ii < 4; ++ii) {
#pragma unroll
      for (int r = 0; r < 4; ++r) {
        const int row = (wm << 6) + (ii << 4) + (fq << 2) + r;   // 0..127
        A3s[(sl << 12) + (row << 5) + (((c >> 3) ^ ((row >> 1) & 3)) << 3) + (c & 7)] =
            f2bf(fmaxf(acc3[ii][jj][r] + b3v[jj], 0.f));
      }
    }
  }

  // ---------------- layer-4 (K=256 from A3 slabs; N=128) ----------------
  f32x4 acc4[4][2];
#pragma unroll
  for (int ii = 0; ii < 4; ++ii)
#pragma unroll
    for (int jj = 0; jj < 2; ++jj)
      acc4[ii][jj] = f32x4{0.f, 0.f, 0.f, 0.f};
  const int nb4 = wn << 5;                   // 0..96

  for (int kt4 = 0; kt4 < 4; ++kt4) {
#pragma unroll
    for (int s = 0; s < 2; ++s) {
      const int kb = (kt4 << 6) + (s << 5);
      gload_lds16(W4T + (size_t)lrow * 256 + (kb + gcol),
                  (char*)W4s + (s << 13) + (w << 10));
    }
    __syncthreads();   // W4 visible; first iter also publishes the A3 funnel
#pragma unroll
    for (int s = 0; s < 2; ++s) {
      const int sl = (kt4 << 1) + s;
      bf16x8 af[4], bfv[2];
#pragma unroll
      for (int ii = 0; ii < 4; ++ii)
        af[ii] = *(const bf16x8*)(A3s + (sl << 12) + (((wm << 6) + (ii << 4) + fr) << 5) + rchunk);
#pragma unroll
      for (int jj = 0; jj < 2; ++jj)
        bfv[jj] = *(const bf16x8*)(W4s + (s << 12) + ((nb4 + (jj << 4) + fr) << 5) + rchunk);
#pragma unroll
      for (int ii = 0; ii < 4; ++ii)
#pragma unroll
        for (int jj = 0; jj < 2; ++jj)
          acc4[ii][jj] = __builtin_amdgcn_mfma_f32_16x16x32_bf16(af[ii], bfv[jj], acc4[ii][jj], 0, 0, 0);
    }
    __syncthreads();
  }

  // ---------------- layer-5 + softmax blend ----------------
  float b4v[2];
#pragma unroll
  for (int jj = 0; jj < 2; ++jj) b4v[jj] = b4[nb4 + (jj << 4) + fr];
#pragma unroll
  for (int ii = 0; ii < 4; ++ii) {
#pragma unroll
    for (int jj = 0; jj < 2; ++jj) {
      const int col = nb4 + (jj << 4) + fr;                      // 0..127
#pragma unroll
      for (int r = 0; r < 4; ++r) {
        const int row = (wm << 6) + (ii << 4) + (fq << 2) + r;   // 0..127
        sh[row * 136 + col] = f2bf(fmaxf(acc4[ii][jj][r] + b4v[jj], 0.f));
      }
    }
  }
  const int cbase = fr << 3;
  float w50[8], w51[8];
#pragma unroll
  for (int j = 0; j < 8; ++j) {
    w50[j] = w5[((cbase + j) << 1) + 0];
    w51[j] = w5[((cbase + j) << 1) + 1];
  }
  const float b50 = b5[0], b51 = b5[1];
  __syncthreads();

#pragma unroll
  for (int rep = 0; rep < 4; ++rep) {
    const int pl = (rep << 3) + w;            // block-local pixel 0..31
    const int row = (pl << 2) + fq;           // branch k = fq
    const u16x8 v = *(const u16x8*)(sh + row * 136 + cbase);
    float s0 = 0.f, s1 = 0.f;
#pragma unroll
    for (int j = 0; j < 8; ++j) {
      const float a = bf2f(v[j]);
      s0 += a * w50[j];
      s1 += a * w51[j];
    }
#pragma unroll
    for (int off = 8; off >= 1; off >>= 1) {
      s0 += __shfl_xor(s0, off, 16);
      s1 += __shfl_xor(s1, off, 16);
    }
    float p0[4], p1[4];
#pragma unroll
    for (int k = 0; k < 4; ++k) {
      p0[k] = __shfl(s0, k << 4, 64) + b50;
      p1[k] = __shfl(s1, k << 4, 64) + b51;
    }
    if (lane == 0) {
      float mx = fmaxf(fmaxf(p1[0], p1[1]), fmaxf(p1[2], p1[3]));
      float e0 = expf(p1[0] - mx), e1 = expf(p1[1] - mx);
      float e2 = expf(p1[2] - mx), e3 = expf(p1[3] - mx);
      outp[gp0 + (m0 >> 2) + pl] =
          (p0[0] * e0 + p0[1] * e1 + p0[2] * e2 + p0[3] * e3) / (e0 + e1 + e2 + e3);
    }
  }
}

// ---------------------------------------------------------------------------
// prep_all: all transposed bf16 weights in one dispatch (+ bf16 w1rel).
// ---------------------------------------------------------------------------
__global__ __launch_bounds__(256)
void prep_all(const float* __restrict__ w1, const float* __restrict__ w2,
              const float* __restrict__ w3, const float* __restrict__ w4,
              u16* __restrict__ W1hrT, u16* __restrict__ W1cellT,
              u16* __restrict__ W2T, u16* __restrict__ W3T, u16* __restrict__ W4T,
              u16* __restrict__ W1rb)
{
  const int idx = blockIdx.x * 256 + threadIdx.x;
  if (idx < 131072) {
    const int n = idx >> 7, k = idx & 127;
    W1hrT[idx] = f2bf(w1[(128 + k) * 1024 + n] + w1[(256 + k) * 1024 + n]);
  } else if (idx < 393216) {
    const int i = idx - 131072;
    const int n = i >> 8, k = i & 255;
    W1cellT[i] = f2bf((k < 128) ? w1[k * 1024 + n] : w1[(128 + k) * 1024 + n]);
  } else if (idx < 917504) {
    const int i = idx - 393216;
    const int n = i >> 10, k = i & 1023;
    W2T[i] = f2bf(w2[k * 512 + n]);
  } else if (idx < 1048576) {
    const int i = idx - 917504;
    const int n = i >> 9, k = i & 511;
    W3T[i] = f2bf(w3[k * 256 + n]);
  } else if (idx < 1081344) {
    const int i = idx - 1048576;
    const int n = i >> 8, k = i & 255;
    W4T[i] = f2bf(w4[k * 128 + n]);
  } else if (idx < 1083392) {
    const int i = idx - 1081344;
    W1rb[i] = f2bf(w1[384 * 1024 + i]);      // w1rel rows 384,385 -> bf16
  }
}

// ---------------------------------------------------------------------------
extern "C" void kernel_launch(void* const* d_in, const int* in_sizes, int n_in,
                              void* d_out, int out_size, void* d_ws, size_t ws_size,
                              hipStream_t stream)
{
  const float* feat  = (const float*)d_in[0];
  const float* coord = (const float*)d_in[1];
  const float* hrg   = (const float*)d_in[2];
  const float* lrg   = (const float*)d_in[3];
  const float* w1 = (const float*)d_in[4];
  const float* b1 = (const float*)d_in[5];
  const float* w2 = (const float*)d_in[6];
  const float* b2 = (const float*)d_in[7];
  const float* w3 = (const float*)d_in[8];
  const float* b3 = (const float*)d_in[9];
  const float* w4 = (const float*)d_in[10];
  const float* b4 = (const float*)d_in[11];
  const float* w5 = (const float*)d_in[12];
  const float* b5 = (const float*)d_in[13];
  float* out = (float*)d_out;

  char* base = (char*)d_ws;
  u16* W1hrT   = (u16*)base;                       // [1024][128]
  u16* W1cellT = W1hrT + 1024 * 128;               // [1024][256]
  u16* W2T     = W1cellT + 1024 * 256;             // [512][1024]
  u16* W3T     = W2T + 512 * 1024;                 // [256][512]
  u16* W4T     = W3T + 256 * 512;                  // [128][256]
  u16* W1rb    = W4T + 128 * 256;                  // [2][1024] bf16 w1rel
  u16* Xcell   = W1rb + 2048;                      // [8192][256]
  u16* Ycell   = Xcell + 8192 * 256;               // [8192][1024] bf16
  u16* Xhr     = Ycell + (size_t)8192 * 1024;      // [131072][128]
  float* relb  = (float*)(Xhr + (size_t)131072 * 128); // [131072][4][2]
  int* cellidx = (int*)(relb + (size_t)131072 * 8);    // [131072][4]
  char* chunk_base = (char*)(cellidx + (size_t)131072 * 4);
  const size_t fixed = (size_t)(chunk_base - base);

  const int NP = 131072;
  // per-pixel chunk bytes: Yhr 2048 + A2 4096 = 6144 (A1 fused away)
  int nc = 1;
  while (nc < 128 && fixed + (size_t)(NP / nc) * 6144ULL > ws_size) nc <<= 1;
  const int CP = NP / nc;
  const int R = CP * 4;

  u16* Yhr = (u16*)chunk_base;          // [CP][1024] bf16 (Yhr + b1 folded)
  u16* A2  = Yhr + (size_t)CP * 1024;   // [R][512] bf16

  prep_all<<<4232, 256, 0, stream>>>(w1, w2, w3, w4, W1hrT, W1cellT, W2T, W3T,
                                     W4T, W1rb);
  gather_hr<<<NP / 64, 256, 0, stream>>>(coord, hrg, Xhr, cellidx, relb);
  prep_cells<<<8192 / 64, 256, 0, stream>>>(feat, lrg, Xcell);
  // Ycell = Xcell @ W1cellT^T (raw bf16)
  gemm_bt<3><<<(8192 / 128) * (1024 / 128), 256, 0, stream>>>(
      Xcell, W1cellT, (void*)Ycell, nullptr, 8192, 1024, 256);

  for (int ch = 0; ch < nc; ++ch) {
    const int gp0 = ch * CP;
    // Yhrb = Xhr_chunk @ W1hrT^T + b1 (MODE 1: bias, no relu)
    gemm_bt<1><<<(CP / 128) * (1024 / 128), 256, 0, stream>>>(
        Xhr + (size_t)gp0 * 128, W1hrT, (void*)Yhr, b1, CP, 1024, 128);
    // fused expand + layer-2: A2 = relu(A1(Yhrb,Ycell,rel) @ W2T^T + b2)
    gemm_l12<<<(R >> 7), 512, 0, stream>>>(
        Yhr, Ycell, W1rb, cellidx, relb, W2T, A2, b2, R, 1024, gp0);
    // layers 3+4+5: 128-row blocks, 512 threads
    tail34<<<R / 128, 512, 0, stream>>>(
        A2, W3T, W4T, b3, b4, w5, b5, out, R, gp0);
  }
}

// Round 12
// 1018.028 us; speedup vs baseline: 1.2411x; 1.0792x over previous
//
#include <hip/hip_runtime.h>

// JIIF fused pipeline v20 = FULL FUSION: tail34 merged into gemm_l12 (l12t).
//   R11 evidence: WRITE_SIZE = exactly A2 size (128MiB; R10's "4.1x write
//   amplification" was an arithmetic error - wrong R). v19 epilogue ~null.
//   gemm_l12 wall 6200cyc/tile vs 2483 MFMA floor is LDS-port + MFMA
//   co-limited; frag re-read cost (192KB/tile) is invariant to wave-grid
//   split -> intra-kernel tuning exhausted. tail34 reads A2 at 2.2TB/s =
//   its dominant cost. l12t: C-tile stays in LDS (swizzled chunk^=row&7 on
//   BOTH store and read sides), W3T staged into freed 32KB, L3 A-frags read
//   the C-tile, funnel->A3 slabs alias dead C rows, L4 + blend (v16 code).
//   Kills 512MiB+512MiB A2 HBM round trip + 8 dispatches; nc 4->2.
// NOTES:
//  - R2(v11): 1-barrier quadrant -> the schedule family that works.
//  - R3(v12): BN=256 fusion FAIL (amortization halved + CONS x2).
//  - R6(v14): CONS under MFMA shadow (kept verbatim here).
//  - R7(v15): MFMA-before-barrier REGRESSED. RULE: barrier -> register-ready
//    MFMA; never dependent ds_reads right after a barrier.
//  - R8(v16): tail34 BM=128/512thr structure (kept verbatim, A-source swap).
//  - R9(v17): native cvt f2bf. BEST standalone = 1093us.
//  - R10(v18): 16-wave REGRESSED: fewer/fatter waves win (32-MFMA clusters).
//  - gemm register budget at the 2-waves/SIMD cliff (124+128 acc): acc dies
//    at C-store before acc3 lives -> peak unchanged. Spill => revert.

typedef unsigned short u16;
typedef unsigned int   u32;
typedef __bf16  bf16x8 __attribute__((ext_vector_type(8)));
typedef float   f32x4  __attribute__((ext_vector_type(4)));
typedef unsigned short u16x8 __attribute__((ext_vector_type(8)));

__device__ __forceinline__ u16 f2bf(float f) {
  __bf16 h = (__bf16)f;                    // native v_cvt_pk_bf16_f32 (RNE)
  return __builtin_bit_cast(u16, h);
}
__device__ __forceinline__ float bf2f(u16 v) {
  return __uint_as_float(((u32)v) << 16);
}
__device__ __forceinline__ void gload_lds16(const void* g, void* l) {
  __builtin_amdgcn_global_load_lds(
      (const __attribute__((address_space(1))) void*)g,
      (__attribute__((address_space(3))) void*)l, 16, 0, 0);
}

// ---------------------------------------------------------------------------
// gather_hr: per-pixel Xhr row (q_guide_hr, bf16[128]) + cellidx[pix][4] + rel[pix][4][2]
// ---------------------------------------------------------------------------
__global__ __launch_bounds__(256)
void gather_hr(const float* __restrict__ coord, const float* __restrict__ hr,
               u16* __restrict__ Xhr, int* __restrict__ cellidx, float* __restrict__ rel)
{
  __shared__ u16 hrT[64 * 130];
  __shared__ int nhrS[64];

  const int tid = threadIdx.x;
  const int pb  = blockIdx.x << 6;        // global pixel base
  const int b   = pb >> 16;
  const int n0  = pb & 65535;
  const float rh = 0.015625f;             // 1/64

  if (tid < 64) {
    const int n = n0 + tid;
    const float cy = coord[(size_t)(b * 65536 + n) * 2 + 0];
    const float cx = coord[(size_t)(b * 65536 + n) * 2 + 1];
    float fyh = (cy + 1.0f) * 128.0f - 0.5f;
    float fxh = (cx + 1.0f) * 128.0f - 0.5f;
    int iyh = (int)floorf(fyh + 0.5f);
    int ixh = (int)floorf(fxh + 0.5f);
    bool vh = (iyh >= 0 && iyh < 256 && ixh >= 0 && ixh < 256);
    nhrS[tid] = vh ? ((iyh << 8) + ixh) : -1;
#pragma unroll
    for (int k = 0; k < 4; ++k) {
      const float vx = (k < 2) ? -1.0f : 1.0f;
      const float vy = (k & 1) ? 1.0f : -1.0f;
      const float cyk = cy + vx * rh;
      const float cxk = cx + vy * rh;
      float fy = (cyk + 1.0f) * 32.0f - 0.5f;
      float fx = (cxk + 1.0f) * 32.0f - 0.5f;
      int iy = (int)floorf(fy + 0.5f);
      int ix = (int)floorf(fx + 0.5f);
      bool valid = (iy >= 0 && iy < 64 && ix >= 0 && ix < 64);
      int iyc = min(max(iy, 0), 63);
      int ixc = min(max(ix, 0), 63);
      float qy = valid ? ((-1.0f + rh) + (2.0f * rh) * (float)iyc) : 0.0f;
      float qx = valid ? ((-1.0f + rh) + (2.0f * rh) * (float)ixc) : 0.0f;
      const int p4 = ((pb + tid) << 2) + k;
      rel[2 * p4 + 0] = (cy - qy) * 64.0f;
      rel[2 * p4 + 1] = (cx - qx) * 64.0f;
      cellidx[p4] = valid ? (b * 4096 + iyc * 64 + ixc) : -1;
    }
  }
  __syncthreads();

  const size_t hb = (size_t)b * 128 * 65536;
  for (int e = tid; e < 64 * 128; e += 256) {
    const int pix = e & 63, c = e >> 6;
    const int n = nhrS[pix];
    const float v = (n >= 0) ? hr[hb + (size_t)c * 65536 + n] : 0.0f;
    hrT[pix * 130 + c] = f2bf(v);
  }
  __syncthreads();

  for (int e = tid; e < 64 * 128; e += 256) {
    const int pix = e >> 7, c = e & 127;
    Xhr[(size_t)(pb + pix) * 128 + c] = hrT[pix * 130 + c];
  }
}

// ---------------------------------------------------------------------------
// prep_cells: Xcell[cell][0:128]=feat, [128:256]=-lr  (bf16)
// ---------------------------------------------------------------------------
__global__ __launch_bounds__(256)
void prep_cells(const float* __restrict__ feat, const float* __restrict__ lr,
                u16* __restrict__ Xcell)
{
  __shared__ u16 t[64 * 258];
  const int tid = threadIdx.x;
  const int cb = blockIdx.x << 6;
  const int b = cb >> 12;
  const int local = cb & 4095;
  const size_t fb = (size_t)b * 128 * 4096;
  for (int e = tid; e < 64 * 128; e += 256) {
    const int cell = e & 63, c = e >> 6;
    const size_t idx = fb + (size_t)c * 4096 + local + cell;
    t[cell * 258 + c]       = f2bf(feat[idx]);
    t[cell * 258 + 128 + c] = (u16)(f2bf(lr[idx]) ^ 0x8000u);
  }
  __syncthreads();
  for (int e = tid; e < 64 * 256; e += 256) {
    const int cell = e >> 8, c = e & 255;
    Xcell[(size_t)(cb + cell) * 256 + c] = t[cell * 258 + c];
  }
}

// ---------------------------------------------------------------------------
// bf16 MFMA GEMM; BK=64 via two 32-k LDS slabs; 128x128 tile.
// MODE 0: C = relu(A@B^T + bias);  MODE 1: C = A@B^T + bias (no relu);
// MODE 3: C = A@B^T (raw). All bf16 out.
// ---------------------------------------------------------------------------
template<int MODE>
__global__ __launch_bounds__(256)
void gemm_bt(const u16* __restrict__ A, const u16* __restrict__ BT,
             void* __restrict__ Cout, const float* __restrict__ bias,
             int M, int N, int K)
{
  __shared__ __align__(16) u16 sh[16384];
  u16* As = sh;
  u16* Bs = sh + 8192;

  const int tid = threadIdx.x;
  const int w = tid >> 6;
  const int lane = tid & 63;
  const int ntn = N >> 7;
  const int nmt = M >> 7;
  int bm, bn;
  if ((nmt & 7) == 0) {
    const int xcd = blockIdx.x & 7;
    const int t = blockIdx.x >> 3;
    bn = t % ntn;
    bm = xcd * (nmt >> 3) + t / ntn;
  } else {
    bm = blockIdx.x / ntn;
    bn = blockIdx.x - bm * ntn;
  }
  const int m0 = bm << 7, n0 = bn << 7;

  const int lrow = tid >> 2;
  const int cc   = tid & 3;
  const int gcol = (cc ^ ((lrow >> 1) & 3)) << 3;

  f32x4 acc[4][4];
#pragma unroll
  for (int ii = 0; ii < 4; ++ii)
#pragma unroll
    for (int jj = 0; jj < 4; ++jj)
      acc[ii][jj] = f32x4{0.f, 0.f, 0.f, 0.f};

  const int mbase = (w & 1) << 6;
  const int nbase = (w >> 1) << 6;
  const int fr = lane & 15;
  const int fq = lane >> 4;
  const int rchunk = (fq ^ ((fr >> 1) & 3)) << 3;

  for (int kt = 0; kt < K; kt += 64) {
#pragma unroll
    for (int s = 0; s < 2; ++s) {
      const int kb = kt + (s << 5);
#pragma unroll
      for (int q = 0; q < 2; ++q) {
        const int mrow = (q << 6) + lrow;
        gload_lds16(A + (size_t)(m0 + mrow) * K + (kb + gcol),
                    (char*)As + (s << 13) + (q << 12) + (w << 10));
        gload_lds16(BT + (size_t)(n0 + mrow) * K + (kb + gcol),
                    (char*)Bs + (s << 13) + (q << 12) + (w << 10));
      }
    }
    __syncthreads();
#pragma unroll
    for (int s = 0; s < 2; ++s) {
      const int so = s << 12;
      bf16x8 af[4], bfv[4];
#pragma unroll
      for (int ii = 0; ii < 4; ++ii) {
        af[ii]  = *(const bf16x8*)(As + so + ((mbase + (ii << 4) + fr) << 5) + rchunk);
        bfv[ii] = *(const bf16x8*)(Bs + so + ((nbase + (ii << 4) + fr) << 5) + rchunk);
      }
#pragma unroll
      for (int ii = 0; ii < 4; ++ii)
#pragma unroll
        for (int jj = 0; jj < 4; ++jj)
          acc[ii][jj] = __builtin_amdgcn_mfma_f32_16x16x32_bf16(af[ii], bfv[jj], acc[ii][jj], 0, 0, 0);
    }
    __syncthreads();
  }

#pragma unroll
  for (int jj = 0; jj < 4; ++jj) {
    const int ncol = n0 + nbase + (jj << 4) + fr;
    const float bi = (MODE == 0 || MODE == 1) ? bias[ncol] : 0.f;
#pragma unroll
    for (int ii = 0; ii < 4; ++ii) {
#pragma unroll
      for (int r = 0; r < 4; ++r) {
        const int mrow = m0 + mbase + (ii << 4) + (fq << 2) + r;
        if (MODE == 0) {
          ((u16*)Cout)[(size_t)mrow * N + ncol] = f2bf(fmaxf(acc[ii][jj][r] + bi, 0.f));
        } else if (MODE == 1) {
          ((u16*)Cout)[(size_t)mrow * N + ncol] = f2bf(acc[ii][jj][r] + bi);
        } else {
          ((u16*)Cout)[(size_t)mrow * N + ncol] = f2bf(acc[ii][jj][r]);
        }
      }
    }
  }
}

// ---------------------------------------------------------------------------
// gemm_l12t: FUSED expand + layer-2 + layers 3/4/5 for a 128-row block.
//   Stage A (v17 K-loop): A2tile = relu(A1 @ W2T^T + b2) -> swizzled LDS
//     C-tile [128][512] (chunk ^= row&7). A1 constructed on the fly.
//   Stage B (v16 tail): layer-3 reads A-frags from the C-tile; W3T staged
//     in freed 32KB; funnel -> A3 slabs (alias dead C rows); layer-4; blend.
//   512 threads / 8 waves; LDS 160KB.
// ---------------------------------------------------------------------------
__global__ __launch_bounds__(512, 2)
void gemm_l12t(const u16* __restrict__ Yhr, const u16* __restrict__ Ycell,
               const u16* __restrict__ W1rb, const int* __restrict__ cellidx,
               const float* __restrict__ rel, const u16* __restrict__ BT,
               const float* __restrict__ bias, const u16* __restrict__ W3T,
               const u16* __restrict__ W4T, const float* __restrict__ b3,
               const float* __restrict__ b4, const float* __restrict__ w5,
               const float* __restrict__ b5, float* __restrict__ outp,
               int M, int K, int gp0)
{
  __shared__ __align__(16) u16 sh[81920];   // 160 KB
  char* shb = (char*)sh;

  const int tid  = threadIdx.x;
  const int w    = tid >> 6;
  const int lane = tid & 63;
  const int wm = w >> 2, wn = w & 3;
  const int nwg = M >> 7;
  int bid = blockIdx.x;
  if ((nwg & 7) == 0) {
    const int cpx = nwg >> 3;
    bid = (bid & 7) * cpx + (bid >> 3);     // bijective XCD swizzle
  }
  const int m0 = bid << 7;
  const int NT = K >> 6;

  // staging/construction thread mapping (l12)
  const int srow = tid >> 3;                // 0..63
  const int cg   = tid & 7;
  const int gk   = (cg ^ (srow & 7)) << 3;  // swizzled source k offset (u16)
  const int swz8 = gk;                      // swizzled LDS chunk (u16)

  // fragment mapping
  const int fr = lane & 15;
  const int fq = lane >> 4;
  const int pk0 = ((fq)     ^ (fr & 7)) << 3;
  const int pk1 = ((4 + fq) ^ (fr & 7)) << 3;
  const int awr = (wm << 6) + fr;           // A frag row base (BM=128)
  const int bwr = (wn << 7) + fr;           // B frag row base (BN=512)

  // per-row persistent gather state (2 rows/thread: rr = srow, 64+srow)
  const int m04 = m0 >> 2;
  const int kk  = srow & 3;
  const int pA  = m04 + (srow >> 2);
  const int pB  = pA + 16;
  const int idxA = (gp0 + pA) * 4 + kk;
  const int idxB = (gp0 + pB) * 4 + kk;
  const int cellA = cellidx[idxA];
  const int cellB = cellidx[idxB];
  const float2 rvA = *(const float2*)(rel + (size_t)idxA * 2);
  const float2 rvB = *(const float2*)(rel + (size_t)idxB * 2);
  const float ryA = rvA.x, rxA = rvA.y, ryB = rvB.x, rxB = rvB.y;
  const u16 mkA = (u16)(cellA >= 0 ? 0xFFFFu : 0u);
  const u16 mkB = (u16)(cellB >= 0 ? 0xFFFFu : 0u);
  const u16x8 mskA = {mkA, mkA, mkA, mkA, mkA, mkA, mkA, mkA};
  const u16x8 mskB = {mkB, mkB, mkB, mkB, mkB, mkB, mkB, mkB};
  const u16* yA = Yhr + (size_t)pA * 1024;
  const u16* yB = Yhr + (size_t)pB * 1024;
  const u16* zA = Ycell + (size_t)max(cellA, 0) * 1024;
  const u16* zB = Ycell + (size_t)max(cellB, 0) * 1024;

  u16x8 yhA, yhB, ycA, ycB, cw0, cw1;

#define A_LOADS(kt1_) do { const int co_ = (kt1_) + (cg << 3); \
    yhA = *(const u16x8*)(yA + co_); yhB = *(const u16x8*)(yB + co_); \
    ycA = *(const u16x8*)(zA + co_); ycB = *(const u16x8*)(zB + co_); \
    cw0 = *(const u16x8*)(W1rb + co_); cw1 = *(const u16x8*)(W1rb + 1024 + co_); } while (0)

#define A_CONS(ab_) do { \
    const u16x8 za_ = ycA & mskA, zb_ = ycB & mskB; \
    u16x8 oA_, oB_; \
    _Pragma("unroll") \
    for (int j_ = 0; j_ < 8; ++j_) { \
      const float f0_ = bf2f(cw0[j_]), f1_ = bf2f(cw1[j_]); \
      float vA_ = bf2f(yhA[j_]) + bf2f(za_[j_]) + ryA * f0_ + rxA * f1_; \
      float vB_ = bf2f(yhB[j_]) + bf2f(zb_[j_]) + ryB * f0_ + rxB * f1_; \
      oA_[j_] = f2bf(fmaxf(vA_, 0.f)); \
      oB_[j_] = f2bf(fmaxf(vB_, 0.f)); \
    } \
    *(u16x8*)(sh + (ab_) + (srow << 6) + swz8) = oA_; \
    *(u16x8*)(sh + (ab_) + ((64 + srow) << 6) + swz8) = oB_; } while (0)

#define STAGE_B(q_, kt_) do { \
    _Pragma("unroll") \
    for (int h_ = 0; h_ < 8; ++h_) \
      gload_lds16(BT + (size_t)((h_ << 6) + srow) * K + (kt_) + gk, \
                  shb + 32768 + ((q_) << 16) + (h_ << 13) + (w << 10)); } while (0)
#define BAR12()   asm volatile("s_barrier" ::: "memory")
#define VMC(n)    asm volatile("s_waitcnt vmcnt(" #n ")" ::: "memory")
#define LGKM0_()  asm volatile("s_waitcnt lgkmcnt(0)" ::: "memory")

  f32x4 acc[4][8];
#pragma unroll
  for (int i = 0; i < 4; ++i)
#pragma unroll
    for (int j = 0; j < 8; ++j)
      acc[i][j] = f32x4{0.f, 0.f, 0.f, 0.f};

  // ---- prologue: build A(0)->buf0, stage B(0)->buf0, prefetch A(1) regs ----
  A_LOADS(0);
  A_CONS(0);
  STAGE_B(0, 0);
  if (NT > 1) { A_LOADS(64); VMC(6); }
  else VMC(0);
  LGKM0_();
  BAR12();

  for (int t = 0; t < NT; ++t) {
    const int Ab = (t & 1) << 13;
    const int Bb = 16384 + ((t & 1) << 15);
    const int p1 = (t + 1) & 1;
    const int kt1 = (t + 1) << 6;
    const bool mA_ = (t + 1 < NT);
    const bool mG_ = (t + 2 < NT);

    // ---- P0: k-slice 0 ----
    bf16x8 a0[4], g0[8];
#pragma unroll
    for (int i = 0; i < 4; ++i)
      a0[i] = *(const bf16x8*)(sh + Ab + ((awr + (i << 4)) << 6) + pk0);
#pragma unroll
    for (int j = 0; j < 8; ++j)
      g0[j] = *(const bf16x8*)(sh + Bb + ((bwr + (j << 4)) << 6) + pk0);
    if (mA_) STAGE_B(p1, kt1);
    __builtin_amdgcn_s_setprio(1);
#pragma unroll
    for (int i = 0; i < 4; ++i)
#pragma unroll
      for (int j = 0; j < 8; ++j)
        acc[i][j] = __builtin_amdgcn_mfma_f32_16x16x32_bf16(a0[i], g0[j], acc[i][j], 0, 0, 0);
    __builtin_amdgcn_s_setprio(0);
    if (mA_) A_CONS(p1 << 13);

    // ---- P1: k-slice 1 ----
    bf16x8 a1[4], g1[8];
#pragma unroll
    for (int i = 0; i < 4; ++i)
      a1[i] = *(const bf16x8*)(sh + Ab + ((awr + (i << 4)) << 6) + pk1);
#pragma unroll
    for (int j = 0; j < 8; ++j)
      g1[j] = *(const bf16x8*)(sh + Bb + ((bwr + (j << 4)) << 6) + pk1);
    if (mG_) A_LOADS((t + 2) << 6);
    if (mG_) VMC(6); else VMC(0);
    LGKM0_();
    BAR12();
    __builtin_amdgcn_s_setprio(1);
#pragma unroll
    for (int i = 0; i < 4; ++i)
#pragma unroll
      for (int j = 0; j < 8; ++j)
        acc[i][j] = __builtin_amdgcn_mfma_f32_16x16x32_bf16(a1[i], g1[j], acc[i][j], 0, 0, 0);
    __builtin_amdgcn_s_setprio(0);
  }

#undef A_LOADS
#undef A_CONS
#undef STAGE_B
#undef BAR12
#undef VMC
#undef LGKM0_

  // ---- A2 tile = relu(acc+bias) -> SWIZZLED LDS C-tile [128][512] ----
  // element (row,col) stored at row*512 + ((col>>3 ^ (row&7))<<3) + (col&7).
  // All K-loop LDS reads were drained before the last barrier -> safe.
#pragma unroll
  for (int j = 0; j < 8; ++j) {
    const int ncol = (wn << 7) + (j << 4) + fr;
    const float bi = bias[ncol];
    const int chnk = ncol >> 3, sub = ncol & 7;
#pragma unroll
    for (int i = 0; i < 4; ++i) {
#pragma unroll
      for (int r = 0; r < 4; ++r) {
        const int row = (wm << 6) + (i << 4) + (fq << 2) + r;
        sh[row * 512 + (((chnk ^ (row & 7)) << 3) | sub)] =
            f2bf(fmaxf(acc[i][j][r] + bi, 0.f));
      }
    }
  }

  // ================= tail (v16 structure; A-source = C-tile) =================
  const int lrow = tid >> 2;                 // 0..127
  const int cc   = tid & 3;
  const int gcol = (cc ^ ((lrow >> 1) & 3)) << 3;
  const int rchunk = (fq ^ ((fr >> 1) & 3)) << 3;
  const int nb3 = wn << 6;
  u16* W3s = sh + 65536;    // 2 slabs x [256][32] u16 @byte 131072 (32KB)
  u16* A3s = sh;            // 8 slabs x [128][32] u16 (aliases dead C rows)
  u16* W4s = sh + 65536;    // 2 slabs x [128][32] u16 (reuses W3s region)

  // ---------------- layer-3 (M 128, N 256, K 512 from C-tile) --------------
  f32x4 acc3[4][4];
#pragma unroll
  for (int ii = 0; ii < 4; ++ii)
#pragma unroll
    for (int jj = 0; jj < 4; ++jj)
      acc3[ii][jj] = f32x4{0.f, 0.f, 0.f, 0.f};

  for (int kt = 0; kt < 512; kt += 64) {
#pragma unroll
    for (int s = 0; s < 2; ++s) {
      const int kb = kt + (s << 5);
#pragma unroll
      for (int q = 0; q < 2; ++q) {
        gload_lds16(W3T + (size_t)((q << 7) + lrow) * 512 + (kb + gcol),
                    (char*)W3s + (s << 14) + (q << 13) + (w << 10));
      }
    }
    __syncthreads();   // publishes W3T slabs; first iter also publishes C-tile
#pragma unroll
    for (int s = 0; s < 2; ++s) {
      const int kb = kt + (s << 5);
      bf16x8 af[4], bfv[4];
#pragma unroll
      for (int ii = 0; ii < 4; ++ii) {
        const int row = (wm << 6) + (ii << 4) + fr;
        af[ii] = *(const bf16x8*)(sh + row * 512 +
                                  ((((kb >> 3) + fq) ^ (row & 7)) << 3));
        bfv[ii] = *(const bf16x8*)(W3s + (s << 13) + ((nb3 + (ii << 4) + fr) << 5) + rchunk);
      }
#pragma unroll
      for (int ii = 0; ii < 4; ++ii)
#pragma unroll
        for (int jj = 0; jj < 4; ++jj)
          acc3[ii][jj] = __builtin_amdgcn_mfma_f32_16x16x32_bf16(af[ii], bfv[jj], acc3[ii][jj], 0, 0, 0);
    }
    __syncthreads();
  }

  // ---------------- funnel: A3 = relu(acc3+b3) -> swizzled LDS slabs -------
  float b3v[4];
#pragma unroll
  for (int jj = 0; jj < 4; ++jj) b3v[jj] = b3[nb3 + (jj << 4) + fr];
#pragma unroll
  for (int jj = 0; jj < 4; ++jj) {
    const int col = nb3 + (jj << 4) + fr;    // 0..255
    const int sl = col >> 5, c = col & 31;
#pragma unroll
    for (int ii = 0; ii < 4; ++ii) {
#pragma unroll
      for (int r = 0; r < 4; ++r) {
        const int row = (wm << 6) + (ii << 4) + (fq << 2) + r;   // 0..127
        A3s[(sl << 12) + (row << 5) + (((c >> 3) ^ ((row >> 1) & 3)) << 3) + (c & 7)] =
            f2bf(fmaxf(acc3[ii][jj][r] + b3v[jj], 0.f));
      }
    }
  }

  // ---------------- layer-4 (K=256 from A3 slabs; N=128) ----------------
  f32x4 acc4[4][2];
#pragma unroll
  for (int ii = 0; ii < 4; ++ii)
#pragma unroll
    for (int jj = 0; jj < 2; ++jj)
      acc4[ii][jj] = f32x4{0.f, 0.f, 0.f, 0.f};
  const int nb4 = wn << 5;                   // 0..96

  for (int kt4 = 0; kt4 < 4; ++kt4) {
#pragma unroll
    for (int s = 0; s < 2; ++s) {
      const int kb = (kt4 << 6) + (s << 5);
      gload_lds16(W4T + (size_t)lrow * 256 + (kb + gcol),
                  (char*)W4s + (s << 13) + (w << 10));
    }
    __syncthreads();   // W4 visible; first iter also publishes the A3 funnel
#pragma unroll
    for (int s = 0; s < 2; ++s) {
      const int sl = (kt4 << 1) + s;
      bf16x8 af[4], bfv[2];
#pragma unroll
      for (int ii = 0; ii < 4; ++ii)
        af[ii] = *(const bf16x8*)(A3s + (sl << 12) + (((wm << 6) + (ii << 4) + fr) << 5) + rchunk);
#pragma unroll
      for (int jj = 0; jj < 2; ++jj)
        bfv[jj] = *(const bf16x8*)(W4s + (s << 12) + ((nb4 + (jj << 4) + fr) << 5) + rchunk);
#pragma unroll
      for (int ii = 0; ii < 4; ++ii)
#pragma unroll
        for (int jj = 0; jj < 2; ++jj)
          acc4[ii][jj] = __builtin_amdgcn_mfma_f32_16x16x32_bf16(af[ii], bfv[jj], acc4[ii][jj], 0, 0, 0);
    }
    __syncthreads();
  }

  // ---------------- layer-5 + softmax blend ----------------
  float b4v[2];
#pragma unroll
  for (int jj = 0; jj < 2; ++jj) b4v[jj] = b4[nb4 + (jj << 4) + fr];
#pragma unroll
  for (int ii = 0; ii < 4; ++ii) {
#pragma unroll
    for (int jj = 0; jj < 2; ++jj) {
      const int col = nb4 + (jj << 4) + fr;                      // 0..127
#pragma unroll
      for (int r = 0; r < 4; ++r) {
        const int row = (wm << 6) + (ii << 4) + (fq << 2) + r;   // 0..127
        sh[row * 136 + col] = f2bf(fmaxf(acc4[ii][jj][r] + b4v[jj], 0.f));
      }
    }
  }
  const int cbase = fr << 3;
  float w50[8], w51[8];
#pragma unroll
  for (int j = 0; j < 8; ++j) {
    w50[j] = w5[((cbase + j) << 1) + 0];
    w51[j] = w5[((cbase + j) << 1) + 1];
  }
  const float b50 = b5[0], b51 = b5[1];
  __syncthreads();

#pragma unroll
  for (int rep = 0; rep < 4; ++rep) {
    const int pl = (rep << 3) + w;            // block-local pixel 0..31
    const int row = (pl << 2) + fq;           // branch k = fq
    const u16x8 v = *(const u16x8*)(sh + row * 136 + cbase);
    float s0 = 0.f, s1 = 0.f;
#pragma unroll
    for (int j = 0; j < 8; ++j) {
      const float a = bf2f(v[j]);
      s0 += a * w50[j];
      s1 += a * w51[j];
    }
#pragma unroll
    for (int off = 8; off >= 1; off >>= 1) {
      s0 += __shfl_xor(s0, off, 16);
      s1 += __shfl_xor(s1, off, 16);
    }
    float p0[4], p1[4];
#pragma unroll
    for (int k = 0; k < 4; ++k) {
      p0[k] = __shfl(s0, k << 4, 64) + b50;
      p1[k] = __shfl(s1, k << 4, 64) + b51;
    }
    if (lane == 0) {
      float mx = fmaxf(fmaxf(p1[0], p1[1]), fmaxf(p1[2], p1[3]));
      float e0 = expf(p1[0] - mx), e1 = expf(p1[1] - mx);
      float e2 = expf(p1[2] - mx), e3 = expf(p1[3] - mx);
      outp[gp0 + (m0 >> 2) + pl] =
          (p0[0] * e0 + p0[1] * e1 + p0[2] * e2 + p0[3] * e3) / (e0 + e1 + e2 + e3);
    }
  }
}

// ---------------------------------------------------------------------------
// prep_all: all transposed bf16 weights in one dispatch (+ bf16 w1rel).
// ---------------------------------------------------------------------------
__global__ __launch_bounds__(256)
void prep_all(const float* __restrict__ w1, const float* __restrict__ w2,
              const float* __restrict__ w3, const float* __restrict__ w4,
              u16* __restrict__ W1hrT, u16* __restrict__ W1cellT,
              u16* __restrict__ W2T, u16* __restrict__ W3T, u16* __restrict__ W4T,
              u16* __restrict__ W1rb)
{
  const int idx = blockIdx.x * 256 + threadIdx.x;
  if (idx < 131072) {
    const int n = idx >> 7, k = idx & 127;
    W1hrT[idx] = f2bf(w1[(128 + k) * 1024 + n] + w1[(256 + k) * 1024 + n]);
  } else if (idx < 393216) {
    const int i = idx - 131072;
    const int n = i >> 8, k = i & 255;
    W1cellT[i] = f2bf((k < 128) ? w1[k * 1024 + n] : w1[(128 + k) * 1024 + n]);
  } else if (idx < 917504) {
    const int i = idx - 393216;
    const int n = i >> 10, k = i & 1023;
    W2T[i] = f2bf(w2[k * 512 + n]);
  } else if (idx < 1048576) {
    const int i = idx - 917504;
    const int n = i >> 9, k = i & 511;
    W3T[i] = f2bf(w3[k * 256 + n]);
  } else if (idx < 1081344) {
    const int i = idx - 1048576;
    const int n = i >> 8, k = i & 255;
    W4T[i] = f2bf(w4[k * 128 + n]);
  } else if (idx < 1083392) {
    const int i = idx - 1081344;
    W1rb[i] = f2bf(w1[384 * 1024 + i]);      // w1rel rows 384,385 -> bf16
  }
}

// ---------------------------------------------------------------------------
extern "C" void kernel_launch(void* const* d_in, const int* in_sizes, int n_in,
                              void* d_out, int out_size, void* d_ws, size_t ws_size,
                              hipStream_t stream)
{
  const float* feat  = (const float*)d_in[0];
  const float* coord = (const float*)d_in[1];
  const float* hrg   = (const float*)d_in[2];
  const float* lrg   = (const float*)d_in[3];
  const float* w1 = (const float*)d_in[4];
  const float* b1 = (const float*)d_in[5];
  const float* w2 = (const float*)d_in[6];
  const float* b2 = (const float*)d_in[7];
  const float* w3 = (const float*)d_in[8];
  const float* b3 = (const float*)d_in[9];
  const float* w4 = (const float*)d_in[10];
  const float* b4 = (const float*)d_in[11];
  const float* w5 = (const float*)d_in[12];
  const float* b5 = (const float*)d_in[13];
  float* out = (float*)d_out;

  char* base = (char*)d_ws;
  u16* W1hrT   = (u16*)base;                       // [1024][128]
  u16* W1cellT = W1hrT + 1024 * 128;               // [1024][256]
  u16* W2T     = W1cellT + 1024 * 256;             // [512][1024]
  u16* W3T     = W2T + 512 * 1024;                 // [256][512]
  u16* W4T     = W3T + 256 * 512;                  // [128][256]
  u16* W1rb    = W4T + 128 * 256;                  // [2][1024] bf16 w1rel
  u16* Xcell   = W1rb + 2048;                      // [8192][256]
  u16* Ycell   = Xcell + 8192 * 256;               // [8192][1024] bf16
  u16* Xhr     = Ycell + (size_t)8192 * 1024;      // [131072][128]
  float* relb  = (float*)(Xhr + (size_t)131072 * 128); // [131072][4][2]
  int* cellidx = (int*)(relb + (size_t)131072 * 8);    // [131072][4]
  char* chunk_base = (char*)(cellidx + (size_t)131072 * 4);
  const size_t fixed = (size_t)(chunk_base - base);

  const int NP = 131072;
  // per-pixel chunk bytes: Yhr 2048 only (A1 and A2 both fused away)
  int nc = 1;
  while (nc < 128 && fixed + (size_t)(NP / nc) * 2048ULL > ws_size) nc <<= 1;
  const int CP = NP / nc;
  const int R = CP * 4;

  u16* Yhr = (u16*)chunk_base;          // [CP][1024] bf16 (Yhr + b1 folded)

  prep_all<<<4232, 256, 0, stream>>>(w1, w2, w3, w4, W1hrT, W1cellT, W2T, W3T,
                                     W4T, W1rb);
  gather_hr<<<NP / 64, 256, 0, stream>>>(coord, hrg, Xhr, cellidx, relb);
  prep_cells<<<8192 / 64, 256, 0, stream>>>(feat, lrg, Xcell);
  // Ycell = Xcell @ W1cellT^T (raw bf16)
  gemm_bt<3><<<(8192 / 128) * (1024 / 128), 256, 0, stream>>>(
      Xcell, W1cellT, (void*)Ycell, nullptr, 8192, 1024, 256);

  for (int ch = 0; ch < nc; ++ch) {
    const int gp0 = ch * CP;
    // Yhrb = Xhr_chunk @ W1hrT^T + b1 (MODE 1: bias, no relu)
    gemm_bt<1><<<(CP / 128) * (1024 / 128), 256, 0, stream>>>(
        Xhr + (size_t)gp0 * 128, W1hrT, (void*)Yhr, b1, CP, 1024, 128);
    // fused expand + layer-2 + layers 3/4/5 (A2 never touches HBM)
    gemm_l12t<<<(R >> 7), 512, 0, stream>>>(
        Yhr, Ycell, W1rb, cellidx, relb, W2T, b2, W3T, W4T, b3, b4, w5, b5,
        out, R, 1024, gp0);
  }
}